// Round 1
// baseline (602.085 us; speedup 1.0000x reference)
//
#include <hip/hip_runtime.h>
#include <cstddef>
#include <cstdint>

// ---------------- problem constants ----------------
#define B_     2
#define NSEQ   2048
#define C_     512
#define H_     8
#define D_     64
#define NFULL  (NSEQ * C_)        // 1048576 elems per batch
#define N4     (NFULL / 4)        // 262144 float4 per batch
#define EPS_   1e-5f
#define LOG2E  1.4426950408889634f
#define RSQRT512 0.044194173824159216f
#define NBLK_RED 256

// ---------------- set-norm statistics (deterministic 2-stage) ----------------
__global__ __launch_bounds__(256) void reduce_partial_k(const float* __restrict__ x,
                                                        float2* __restrict__ partials)
{
    int b = blockIdx.y;
    const float4* xb = reinterpret_cast<const float4*>(x + (size_t)b * NFULL);
    int base = blockIdx.x * 1024 + threadIdx.x;
    float s = 0.f, ss = 0.f;
#pragma unroll
    for (int i = 0; i < 4; ++i) {
        float4 v = xb[base + i * 256];
        s  += (v.x + v.y) + (v.z + v.w);
        ss += (v.x * v.x + v.y * v.y) + (v.z * v.z + v.w * v.w);
    }
    __shared__ float rs[256], rss[256];
    rs[threadIdx.x] = s; rss[threadIdx.x] = ss;
    __syncthreads();
    for (int off = 128; off > 0; off >>= 1) {
        if (threadIdx.x < off) {
            rs[threadIdx.x]  += rs[threadIdx.x + off];
            rss[threadIdx.x] += rss[threadIdx.x + off];
        }
        __syncthreads();
    }
    if (threadIdx.x == 0)
        partials[b * NBLK_RED + blockIdx.x] = make_float2(rs[0], rss[0]);
}

__global__ __launch_bounds__(NBLK_RED) void reduce_final_k(const float2* __restrict__ partials,
                                                           float2* __restrict__ stat)
{
    int b = blockIdx.x;
    float2 p = partials[b * NBLK_RED + threadIdx.x];
    __shared__ float rs[256], rss[256];
    rs[threadIdx.x] = p.x; rss[threadIdx.x] = p.y;
    __syncthreads();
    for (int off = 128; off > 0; off >>= 1) {
        if (threadIdx.x < off) {
            rs[threadIdx.x]  += rs[threadIdx.x + off];
            rss[threadIdx.x] += rss[threadIdx.x + off];
        }
        __syncthreads();
    }
    if (threadIdx.x == 0) {
        float mu  = rs[0] / (float)NFULL;
        float var = rss[0] / (float)NFULL - mu * mu;
        stat[b] = make_float2(mu, rsqrtf(var + EPS_));
    }
}

// ---------------- fused normalize: y = (x-mu)*inv*gamma[f] + beta[f] ----------------
__global__ __launch_bounds__(256) void normalize_k(const float* __restrict__ x,
                                                   const float2* __restrict__ stat,
                                                   const float* __restrict__ gamma,
                                                   const float* __restrict__ beta,
                                                   float* __restrict__ y)
{
    int i4 = blockIdx.x * 256 + threadIdx.x;   // 0 .. 2*N4-1
    int b  = i4 / N4;
    int f4 = i4 & 127;                          // (C_/4) == 128, N4 % 128 == 0
    float2 st = stat[b];
    float4 v  = reinterpret_cast<const float4*>(x)[i4];
    float4 g  = reinterpret_cast<const float4*>(gamma)[f4];
    float4 be = reinterpret_cast<const float4*>(beta)[f4];
    float4 r;
    r.x = (v.x - st.x) * st.y * g.x + be.x;
    r.y = (v.y - st.x) * st.y * g.y + be.y;
    r.z = (v.z - st.x) * st.y * g.z + be.z;
    r.w = (v.w - st.x) * st.y * g.w + be.w;
    reinterpret_cast<float4*>(y)[i4] = r;
}

// ---------------- fp32 tiled GEMM: C[M=4096][512] = A[4096][512] @ W[512][512] (+bias, opt relu+res) ----------------
// BM=128 BN=64 BK=32, 256 threads (16x16), 8x4 micro-tile
__device__ __forceinline__ void gemm_body(const float* __restrict__ A, const float* __restrict__ W,
                                          const float* __restrict__ bias, const float* __restrict__ res,
                                          float* __restrict__ C)
{
    __shared__ float At[32][128];   // transposed A tile [k][m]
    __shared__ float Bs[32][64];    // [k][n]
    int tid = threadIdx.x;
    int ty = tid >> 4, tx = tid & 15;
    int rowbase = blockIdx.x * 128;
    int colbase = blockIdx.y * 64;
    float acc[8][4];
#pragma unroll
    for (int j = 0; j < 8; ++j)
#pragma unroll
        for (int l = 0; l < 4; ++l) acc[j][l] = 0.f;

    for (int kt = 0; kt < 512; kt += 32) {
#pragma unroll
        for (int i = 0; i < 4; ++i) {           // A tile: 128x32 = 1024 float4
            int f = tid + i * 256;
            int r = f >> 3, c4 = (f & 7) << 2;
            float4 v = *reinterpret_cast<const float4*>(A + (size_t)(rowbase + r) * 512 + kt + c4);
            At[c4 + 0][r] = v.x; At[c4 + 1][r] = v.y; At[c4 + 2][r] = v.z; At[c4 + 3][r] = v.w;
        }
#pragma unroll
        for (int i = 0; i < 2; ++i) {           // B tile: 32x64 = 512 float4
            int f = tid + i * 256;
            int r = f >> 4, c4 = (f & 15) << 2;
            *reinterpret_cast<float4*>(&Bs[r][c4]) =
                *reinterpret_cast<const float4*>(W + (size_t)(kt + r) * 512 + colbase + c4);
        }
        __syncthreads();
#pragma unroll
        for (int k = 0; k < 32; ++k) {
            float4 a0 = *reinterpret_cast<const float4*>(&At[k][ty * 8]);
            float4 a1 = *reinterpret_cast<const float4*>(&At[k][ty * 8 + 4]);
            float4 bv = *reinterpret_cast<const float4*>(&Bs[k][tx * 4]);
            float a[8] = {a0.x, a0.y, a0.z, a0.w, a1.x, a1.y, a1.z, a1.w};
#pragma unroll
            for (int j = 0; j < 8; ++j) {
                acc[j][0] += a[j] * bv.x; acc[j][1] += a[j] * bv.y;
                acc[j][2] += a[j] * bv.z; acc[j][3] += a[j] * bv.w;
            }
        }
        __syncthreads();
    }
    float4 b4 = *reinterpret_cast<const float4*>(bias + colbase + tx * 4);
#pragma unroll
    for (int j = 0; j < 8; ++j) {
        int row = rowbase + ty * 8 + j;
        size_t off = (size_t)row * 512 + colbase + tx * 4;
        float4 c;
        c.x = acc[j][0] + b4.x; c.y = acc[j][1] + b4.y;
        c.z = acc[j][2] + b4.z; c.w = acc[j][3] + b4.w;
        if (res) {
            float4 r4 = *reinterpret_cast<const float4*>(res + off);
            c.x = r4.x + fmaxf(c.x, 0.f); c.y = r4.y + fmaxf(c.y, 0.f);
            c.z = r4.z + fmaxf(c.z, 0.f); c.w = r4.w + fmaxf(c.w, 0.f);
        }
        *reinterpret_cast<float4*>(C + off) = c;
    }
}

__global__ __launch_bounds__(256) void gemm3_k(const float* __restrict__ q_n, const float* __restrict__ kv_n,
                                               const float* __restrict__ Wq, const float* __restrict__ bq,
                                               const float* __restrict__ Wk, const float* __restrict__ bk,
                                               const float* __restrict__ Wv, const float* __restrict__ bv,
                                               float* __restrict__ qp, float* __restrict__ kp, float* __restrict__ vp)
{
    int z = blockIdx.z;
    const float* A    = (z == 0) ? q_n : kv_n;
    const float* W    = (z == 0) ? Wq : (z == 1) ? Wk : Wv;
    const float* bias = (z == 0) ? bq : (z == 1) ? bk : bv;
    float* C          = (z == 0) ? qp : (z == 1) ? kp : vp;
    gemm_body(A, W, bias, nullptr, C);
}

__global__ __launch_bounds__(256) void gemm_out_k(const float* __restrict__ o_n, const float* __restrict__ Wo,
                                                  const float* __restrict__ bo, const float* __restrict__ res,
                                                  float* __restrict__ out)
{
    gemm_body(o_n, Wo, bo, res, out);
}

// ---------------- flash attention, fp32, thread = one q-row ----------------
// block = 256 threads = 4 waves; each wave owns the SAME 64 q-rows?? no:
// each wave owns the same 64 q-rows' lane mapping but a DIFFERENT quarter of KV (512 kv),
// merged at the end (flash-decoding style split).
#define KT 32
__global__ __launch_bounds__(256) void attn_k(const float* __restrict__ qp, const float* __restrict__ kp,
                                              const float* __restrict__ vp, const float* __restrict__ query,
                                              float* __restrict__ out_pre)
{
    __shared__ float smem[4 * KT * 64 * 2];    // 16384 floats: staging K|V, later overlaid by o-partials
    __shared__ float mls[4][64][2];
    int qt = blockIdx.x, h = blockIdx.y, b = blockIdx.z;
    int tid = threadIdx.x, w = tid >> 6, lane = tid & 63;
    int qrow = qt * 64 + lane;

    float* Ks = smem + w * KT * 64;
    float* Vs = smem + 4 * KT * 64 + w * KT * 64;

    const float* qptr = qp + ((size_t)(b * NSEQ) + qrow) * 512 + h * 64;
    float q[64];
#pragma unroll
    for (int i = 0; i < 16; ++i) {
        float4 v = *reinterpret_cast<const float4*>(qptr + i * 4);
        q[i * 4] = v.x; q[i * 4 + 1] = v.y; q[i * 4 + 2] = v.z; q[i * 4 + 3] = v.w;
    }
    float o[64];
#pragma unroll
    for (int i = 0; i < 64; ++i) o[i] = 0.f;
    float m = -3.0e38f, l = 0.f;

    int kvbase = w * 512;
    for (int ch = 0; ch < 512; ch += KT) {
        const float* kb = kp + ((size_t)(b * NSEQ) + kvbase + ch) * 512 + h * 64;
        const float* vb = vp + ((size_t)(b * NSEQ) + kvbase + ch) * 512 + h * 64;
#pragma unroll
        for (int i = 0; i < 8; ++i) {           // KT*64 floats = 512 float4 / 64 lanes = 8 each
            int f = lane + i * 64;
            int r = f >> 4, c4 = (f & 15) << 2;
            *reinterpret_cast<float4*>(&Ks[r * 64 + c4]) =
                *reinterpret_cast<const float4*>(kb + (size_t)r * 512 + c4);
            *reinterpret_cast<float4*>(&Vs[r * 64 + c4]) =
                *reinterpret_cast<const float4*>(vb + (size_t)r * 512 + c4);
        }
        __syncthreads();
#pragma unroll 1
        for (int j = 0; j < KT; ++j) {
            float s0 = 0.f, s1 = 0.f, s2 = 0.f, s3 = 0.f;
#pragma unroll
            for (int i = 0; i < 16; ++i) {      // broadcast reads
                float4 kf = *reinterpret_cast<const float4*>(&Ks[j * 64 + i * 4]);
                s0 += q[i * 4] * kf.x;     s1 += q[i * 4 + 1] * kf.y;
                s2 += q[i * 4 + 2] * kf.z; s3 += q[i * 4 + 3] * kf.w;
            }
            float s = ((s0 + s1) + (s2 + s3)) * RSQRT512;
            if (s > m) {                        // rare after warm-up
                float c = exp2f((m - s) * LOG2E);
#pragma unroll
                for (int i = 0; i < 64; ++i) o[i] *= c;
                l *= c; m = s;
            }
            float p = exp2f((s - m) * LOG2E);
            l += p;
#pragma unroll
            for (int i = 0; i < 16; ++i) {
                float4 vf = *reinterpret_cast<const float4*>(&Vs[j * 64 + i * 4]);
                o[i * 4]     += p * vf.x; o[i * 4 + 1] += p * vf.y;
                o[i * 4 + 2] += p * vf.z; o[i * 4 + 3] += p * vf.w;
            }
        }
        __syncthreads();
    }

    // publish per-wave partials (overlay staging buffer — safe: barrier above)
    mls[w][lane][0] = m; mls[w][lane][1] = l;
    float* osh = smem;                           // [4][64][64]
#pragma unroll
    for (int i = 0; i < 16; ++i)
        *reinterpret_cast<float4*>(&osh[(w * 64 + lane) * 64 + i * 4]) =
            make_float4(o[i * 4], o[i * 4 + 1], o[i * 4 + 2], o[i * 4 + 3]);
    __syncthreads();

    // merge 4 KV-splits: thread t -> row r = t/4, dim quarter = t%4
    int r = tid >> 2, part = tid & 3;
    float M = mls[0][r][0];
#pragma unroll
    for (int ww = 1; ww < 4; ++ww) M = fmaxf(M, mls[ww][r][0]);
    float ew[4]; float L = 0.f;
#pragma unroll
    for (int ww = 0; ww < 4; ++ww) {
        ew[ww] = exp2f((mls[ww][r][0] - M) * LOG2E);
        L += ew[ww] * mls[ww][r][1];
    }
    float invL = 1.0f / L;
    size_t gbase = ((size_t)(b * NSEQ) + qt * 64 + r) * 512 + h * 64 + part * 16;
#pragma unroll
    for (int i4 = 0; i4 < 4; ++i4) {
        float4 acc = make_float4(0.f, 0.f, 0.f, 0.f);
#pragma unroll
        for (int ww = 0; ww < 4; ++ww) {
            float4 ov = *reinterpret_cast<const float4*>(&osh[(ww * 64 + r) * 64 + part * 16 + i4 * 4]);
            acc.x += ew[ww] * ov.x; acc.y += ew[ww] * ov.y;
            acc.z += ew[ww] * ov.z; acc.w += ew[ww] * ov.w;
        }
        float4 qr = *reinterpret_cast<const float4*>(query + gbase + i4 * 4);
        float4 o4;
        o4.x = qr.x + acc.x * invL; o4.y = qr.y + acc.y * invL;
        o4.z = qr.z + acc.z * invL; o4.w = qr.w + acc.w * invL;
        *reinterpret_cast<float4*>(out_pre + gbase + i4 * 4) = o4;
    }
}

// ---------------- launcher ----------------
extern "C" void kernel_launch(void* const* d_in, const int* in_sizes, int n_in,
                              void* d_out, int out_size, void* d_ws, size_t ws_size,
                              hipStream_t stream)
{
    const float* query     = (const float*)d_in[0];
    const float* key_value = (const float*)d_in[1];
    const float* Wq = (const float*)d_in[2];
    const float* bq = (const float*)d_in[3];
    const float* Wk = (const float*)d_in[4];
    const float* bk = (const float*)d_in[5];
    const float* Wv = (const float*)d_in[6];
    const float* bv = (const float*)d_in[7];
    const float* Wo = (const float*)d_in[8];
    const float* bo = (const float*)d_in[9];
    const float* g_q = (const float*)d_in[10];
    const float* be_q = (const float*)d_in[11];
    const float* g_k = (const float*)d_in[12];
    const float* be_k = (const float*)d_in[13];
    const float* g_o = (const float*)d_in[14];
    const float* be_o = (const float*)d_in[15];
    float* out = (float*)d_out;

    float* ws = (float*)d_ws;
    float2* part_q  = (float2*)ws;                  // [2][256]
    float2* part_kv = part_q + 2 * NBLK_RED;
    float2* part_o  = part_kv + 2 * NBLK_RED;
    float2* stat_q  = part_o + 2 * NBLK_RED;        // [2]
    float2* stat_kv = stat_q + 2;
    float2* stat_o  = stat_kv + 2;

    const size_t SZ = (size_t)B_ * NFULL;           // 2M floats
    float* big     = ws + 4096;
    float* q_n     = big;
    float* kv_n    = q_n + SZ;
    float* qp      = kv_n + SZ;
    float* kp      = qp + SZ;
    float* vp      = kp + SZ;
    float* out_pre = vp + SZ;
    float* o_n     = out_pre + SZ;
    // total ws use: 4096 + 7*2097152 floats ~= 58.7 MB

    dim3 blk(256);

    reduce_partial_k<<<dim3(NBLK_RED, B_), blk, 0, stream>>>(query, part_q);
    reduce_partial_k<<<dim3(NBLK_RED, B_), blk, 0, stream>>>(key_value, part_kv);
    reduce_final_k<<<dim3(B_), blk, 0, stream>>>(part_q, stat_q);
    reduce_final_k<<<dim3(B_), blk, 0, stream>>>(part_kv, stat_kv);
    normalize_k<<<dim3(2048), blk, 0, stream>>>(query, stat_q, g_q, be_q, q_n);
    normalize_k<<<dim3(2048), blk, 0, stream>>>(key_value, stat_kv, g_k, be_k, kv_n);

    gemm3_k<<<dim3(32, 8, 3), blk, 0, stream>>>(q_n, kv_n, Wq, bq, Wk, bk, Wv, bv, qp, kp, vp);

    attn_k<<<dim3(32, H_, B_), blk, 0, stream>>>(qp, kp, vp, query, out_pre);

    reduce_partial_k<<<dim3(NBLK_RED, B_), blk, 0, stream>>>(out_pre, part_o);
    reduce_final_k<<<dim3(B_), blk, 0, stream>>>(part_o, stat_o);
    normalize_k<<<dim3(2048), blk, 0, stream>>>(out_pre, stat_o, g_o, be_o, o_n);

    gemm_out_k<<<dim3(32, 8), blk, 0, stream>>>(o_n, Wo, bo, out_pre, out);
}

// Round 2
// 269.613 us; speedup vs baseline: 2.2331x; 2.2331x over previous
//
#include <hip/hip_runtime.h>
#include <cstddef>
#include <cstdint>

// ---------------- problem constants ----------------
#define B_     2
#define NSEQ   2048
#define C_     512
#define H_     8
#define D_     64
#define NFULL  (NSEQ * C_)        // 1048576 elems per batch
#define N4     (NFULL / 4)        // 262144 float4 per batch
#define EPS_   1e-5f
#define LOG2E  1.4426950408889634f
#define RSQRT512 0.044194173824159216f
#define NBLK_RED 256

typedef __attribute__((ext_vector_type(8))) short bf16x8;
typedef __attribute__((ext_vector_type(4))) float f32x4;

__device__ __forceinline__ unsigned short f2b(float x) {
    unsigned int u = __float_as_uint(x);
    u += 0x7FFFu + ((u >> 16) & 1u);          // RNE
    return (unsigned short)(u >> 16);
}

// ---------------- set-norm statistics (deterministic 2-stage) ----------------
__global__ __launch_bounds__(256) void reduce_partial_k(const float* __restrict__ x,
                                                        float2* __restrict__ partials)
{
    int b = blockIdx.y;
    const float4* xb = reinterpret_cast<const float4*>(x + (size_t)b * NFULL);
    int base = blockIdx.x * 1024 + threadIdx.x;
    float s = 0.f, ss = 0.f;
#pragma unroll
    for (int i = 0; i < 4; ++i) {
        float4 v = xb[base + i * 256];
        s  += (v.x + v.y) + (v.z + v.w);
        ss += (v.x * v.x + v.y * v.y) + (v.z * v.z + v.w * v.w);
    }
    __shared__ float rs[256], rss[256];
    rs[threadIdx.x] = s; rss[threadIdx.x] = ss;
    __syncthreads();
    for (int off = 128; off > 0; off >>= 1) {
        if (threadIdx.x < off) {
            rs[threadIdx.x]  += rs[threadIdx.x + off];
            rss[threadIdx.x] += rss[threadIdx.x + off];
        }
        __syncthreads();
    }
    if (threadIdx.x == 0)
        partials[b * NBLK_RED + blockIdx.x] = make_float2(rs[0], rss[0]);
}

__global__ __launch_bounds__(NBLK_RED) void reduce_final_k(const float2* __restrict__ partials,
                                                           float2* __restrict__ stat)
{
    int b = blockIdx.x;
    float2 p = partials[b * NBLK_RED + threadIdx.x];
    __shared__ float rs[256], rss[256];
    rs[threadIdx.x] = p.x; rss[threadIdx.x] = p.y;
    __syncthreads();
    for (int off = 128; off > 0; off >>= 1) {
        if (threadIdx.x < off) {
            rs[threadIdx.x]  += rs[threadIdx.x + off];
            rss[threadIdx.x] += rss[threadIdx.x + off];
        }
        __syncthreads();
    }
    if (threadIdx.x == 0) {
        float mu  = rs[0] / (float)NFULL;
        float var = rss[0] / (float)NFULL - mu * mu;
        stat[b] = make_float2(mu, rsqrtf(var + EPS_));
    }
}

// ---------------- fused normalize ----------------
__global__ __launch_bounds__(256) void normalize_k(const float* __restrict__ x,
                                                   const float2* __restrict__ stat,
                                                   const float* __restrict__ gamma,
                                                   const float* __restrict__ beta,
                                                   float* __restrict__ y)
{
    int i4 = blockIdx.x * 256 + threadIdx.x;
    int b  = i4 / N4;
    int f4 = i4 & 127;
    float2 st = stat[b];
    float4 v  = reinterpret_cast<const float4*>(x)[i4];
    float4 g  = reinterpret_cast<const float4*>(gamma)[f4];
    float4 be = reinterpret_cast<const float4*>(beta)[f4];
    float4 r;
    r.x = (v.x - st.x) * st.y * g.x + be.x;
    r.y = (v.y - st.x) * st.y * g.y + be.y;
    r.z = (v.z - st.x) * st.y * g.z + be.z;
    r.w = (v.w - st.x) * st.y * g.w + be.w;
    reinterpret_cast<float4*>(y)[i4] = r;
}

// ---------------- fp32 tiled GEMM (unchanged this round) ----------------
__device__ __forceinline__ void gemm_body(const float* __restrict__ A, const float* __restrict__ W,
                                          const float* __restrict__ bias, const float* __restrict__ res,
                                          float* __restrict__ C)
{
    __shared__ float At[32][128];
    __shared__ float Bs[32][64];
    int tid = threadIdx.x;
    int ty = tid >> 4, tx = tid & 15;
    int rowbase = blockIdx.x * 128;
    int colbase = blockIdx.y * 64;
    float acc[8][4];
#pragma unroll
    for (int j = 0; j < 8; ++j)
#pragma unroll
        for (int l = 0; l < 4; ++l) acc[j][l] = 0.f;

    for (int kt = 0; kt < 512; kt += 32) {
#pragma unroll
        for (int i = 0; i < 4; ++i) {
            int f = tid + i * 256;
            int r = f >> 3, c4 = (f & 7) << 2;
            float4 v = *reinterpret_cast<const float4*>(A + (size_t)(rowbase + r) * 512 + kt + c4);
            At[c4 + 0][r] = v.x; At[c4 + 1][r] = v.y; At[c4 + 2][r] = v.z; At[c4 + 3][r] = v.w;
        }
#pragma unroll
        for (int i = 0; i < 2; ++i) {
            int f = tid + i * 256;
            int r = f >> 4, c4 = (f & 15) << 2;
            *reinterpret_cast<float4*>(&Bs[r][c4]) =
                *reinterpret_cast<const float4*>(W + (size_t)(kt + r) * 512 + colbase + c4);
        }
        __syncthreads();
#pragma unroll
        for (int k = 0; k < 32; ++k) {
            float4 a0 = *reinterpret_cast<const float4*>(&At[k][ty * 8]);
            float4 a1 = *reinterpret_cast<const float4*>(&At[k][ty * 8 + 4]);
            float4 bv = *reinterpret_cast<const float4*>(&Bs[k][tx * 4]);
            float a[8] = {a0.x, a0.y, a0.z, a0.w, a1.x, a1.y, a1.z, a1.w};
#pragma unroll
            for (int j = 0; j < 8; ++j) {
                acc[j][0] += a[j] * bv.x; acc[j][1] += a[j] * bv.y;
                acc[j][2] += a[j] * bv.z; acc[j][3] += a[j] * bv.w;
            }
        }
        __syncthreads();
    }
    float4 b4 = *reinterpret_cast<const float4*>(bias + colbase + tx * 4);
#pragma unroll
    for (int j = 0; j < 8; ++j) {
        int row = rowbase + ty * 8 + j;
        size_t off = (size_t)row * 512 + colbase + tx * 4;
        float4 c;
        c.x = acc[j][0] + b4.x; c.y = acc[j][1] + b4.y;
        c.z = acc[j][2] + b4.z; c.w = acc[j][3] + b4.w;
        if (res) {
            float4 r4 = *reinterpret_cast<const float4*>(res + off);
            c.x = r4.x + fmaxf(c.x, 0.f); c.y = r4.y + fmaxf(c.y, 0.f);
            c.z = r4.z + fmaxf(c.z, 0.f); c.w = r4.w + fmaxf(c.w, 0.f);
        }
        *reinterpret_cast<float4*>(C + off) = c;
    }
}

__global__ __launch_bounds__(256) void gemm3_k(const float* __restrict__ q_n, const float* __restrict__ kv_n,
                                               const float* __restrict__ Wq, const float* __restrict__ bq,
                                               const float* __restrict__ Wk, const float* __restrict__ bk,
                                               const float* __restrict__ Wv, const float* __restrict__ bv,
                                               float* __restrict__ qp, float* __restrict__ kp, float* __restrict__ vp)
{
    int z = blockIdx.z;
    const float* A    = (z == 0) ? q_n : kv_n;
    const float* W    = (z == 0) ? Wq : (z == 1) ? Wk : Wv;
    const float* bias = (z == 0) ? bq : (z == 1) ? bk : bv;
    float* C          = (z == 0) ? qp : (z == 1) ? kp : vp;
    gemm_body(A, W, bias, nullptr, C);
}

__global__ __launch_bounds__(256) void gemm_out_k(const float* __restrict__ o_n, const float* __restrict__ Wo,
                                                  const float* __restrict__ bo, const float* __restrict__ res,
                                                  float* __restrict__ out)
{
    gemm_body(o_n, Wo, bo, res, out);
}

// ---------------- fp32 -> bf16 conversions ----------------
__global__ __launch_bounds__(256) void f32_to_bf16_k(const float* __restrict__ src,
                                                     unsigned short* __restrict__ dst)
{
    int i = blockIdx.x * 256 + threadIdx.x;     // over N4*B_ float4s (524288)
    float4 v = reinterpret_cast<const float4*>(src)[i];
    ushort4 o;
    o.x = f2b(v.x); o.y = f2b(v.y); o.z = f2b(v.z); o.w = f2b(v.w);
    reinterpret_cast<ushort4*>(dst)[i] = o;
}

// vp [b][n][h*64+d] fp32  ->  Vt [(b*8+h)*64+d][n] bf16
__global__ __launch_bounds__(256) void transpose_v_k(const float* __restrict__ vp,
                                                     unsigned short* __restrict__ Vt)
{
    __shared__ unsigned short T[64][68];
    int nb = blockIdx.x * 64, h = blockIdx.y, b = blockIdx.z;
    int tid = threadIdx.x;
#pragma unroll
    for (int i = 0; i < 4; ++i) {
        int idx = tid + i * 256;
        int n = idx >> 4, d4 = (idx & 15) * 4;
        float4 v = *reinterpret_cast<const float4*>(vp + ((size_t)(b * NSEQ + nb + n)) * C_ + h * D_ + d4);
        ushort4 o;
        o.x = f2b(v.x); o.y = f2b(v.y); o.z = f2b(v.z); o.w = f2b(v.w);
        *reinterpret_cast<ushort4*>(&T[n][d4]) = o;
    }
    __syncthreads();
#pragma unroll
    for (int i = 0; i < 4; ++i) {
        int idx = tid + i * 256;
        int d = idx >> 4, n4 = (idx & 15) * 4;
        ushort4 o;
        o.x = T[n4 + 0][d]; o.y = T[n4 + 1][d]; o.z = T[n4 + 2][d]; o.w = T[n4 + 3][d];
        *reinterpret_cast<ushort4*>(Vt + ((size_t)((b * H_ + h) * D_ + d)) * NSEQ + nb + n4) = o;
    }
}

// ---------------- MFMA flash attention ----------------
// block = 4 waves x 64; wave owns 16 q-rows. grid = (NSEQ/64, H, B).
// KV chunk = 64 keys staged in LDS (bf16, +8 pad). P transposed via per-wave LDS tile.
__global__ __launch_bounds__(256) void attn2_k(const unsigned short* __restrict__ Qb,
                                               const unsigned short* __restrict__ Kb,
                                               const unsigned short* __restrict__ Vt,
                                               const float* __restrict__ query,
                                               float* __restrict__ out_pre)
{
    __shared__ unsigned short Ks[64][72];
    __shared__ unsigned short Vts[64][72];
    __shared__ unsigned short Pl[4][16][72];

    const int tid = threadIdx.x;
    const int w = tid >> 6, lane = tid & 63;
    const int l15 = lane & 15, l4 = lane >> 4;
    const int h = blockIdx.y, b = blockIdx.z;
    const int qrow0 = blockIdx.x * 64 + w * 16;

    // Q A-fragments (row = lane&15, k = (lane>>4)*8 + j), two K=32 halves of d=64
    const unsigned short* Qbase = Qb + ((size_t)(b * NSEQ + qrow0 + l15)) * C_ + h * D_ + l4 * 8;
    bf16x8 qf0 = *reinterpret_cast<const bf16x8*>(Qbase);
    bf16x8 qf1 = *reinterpret_cast<const bf16x8*>(Qbase + 32);

    f32x4 acc[4];
#pragma unroll
    for (int dg = 0; dg < 4; ++dg) acc[dg] = (f32x4){0.f, 0.f, 0.f, 0.f};
    float m[4], l[4];
#pragma unroll
    for (int r = 0; r < 4; ++r) { m[r] = -3.0e38f; l[r] = 0.f; }

    const float A_ = RSQRT512 * LOG2E;          // softmax in log2 domain
    const unsigned short* Kbase = Kb + ((size_t)(b * NSEQ)) * C_ + h * D_;
    const unsigned short* Vbase = Vt + ((size_t)((b * H_ + h) * D_)) * NSEQ;

    for (int ch = 0; ch < NSEQ; ch += 64) {
        // ---- stage K chunk [64key][64d] and Vt chunk [64d][64key] ----
#pragma unroll
        for (int p = 0; p < 2; ++p) {
            int f = tid + p * 256;
            int r0 = f >> 3, g = f & 7;
            uint4 kd = *reinterpret_cast<const uint4*>(Kbase + (size_t)(ch + r0) * C_ + g * 8);
            *reinterpret_cast<uint4*>(&Ks[r0][g * 8]) = kd;
            uint4 vd = *reinterpret_cast<const uint4*>(Vbase + (size_t)r0 * NSEQ + ch + g * 8);
            *reinterpret_cast<uint4*>(&Vts[r0][g * 8]) = vd;
        }
        __syncthreads();

        // ---- S = Q K^T for 16q x 64k ----
        f32x4 S[4];
#pragma unroll
        for (int kg = 0; kg < 4; ++kg) {
            bf16x8 kb0 = *reinterpret_cast<const bf16x8*>(&Ks[kg * 16 + l15][l4 * 8]);
            bf16x8 kb1 = *reinterpret_cast<const bf16x8*>(&Ks[kg * 16 + l15][32 + l4 * 8]);
            f32x4 s = (f32x4){0.f, 0.f, 0.f, 0.f};
            s = __builtin_amdgcn_mfma_f32_16x16x32_bf16(qf0, kb0, s, 0, 0, 0);
            s = __builtin_amdgcn_mfma_f32_16x16x32_bf16(qf1, kb1, s, 0, 0, 0);
            S[kg] = s;
        }

        // ---- online softmax (rows = (lane>>4)*4 + r) ----
#pragma unroll
        for (int r = 0; r < 4; ++r) {
            float rm = fmaxf(fmaxf(S[0][r], S[1][r]), fmaxf(S[2][r], S[3][r]));
            rm = fmaxf(rm, __shfl_xor(rm, 1));
            rm = fmaxf(rm, __shfl_xor(rm, 2));
            rm = fmaxf(rm, __shfl_xor(rm, 4));
            rm = fmaxf(rm, __shfl_xor(rm, 8));
            float zr = rm * A_;
            float mn = fmaxf(m[r], zr);
            float c  = exp2f(m[r] - mn);
            m[r] = mn; l[r] *= c;
#pragma unroll
            for (int dg = 0; dg < 4; ++dg) acc[dg][r] *= c;
            float p0 = exp2f(fmaf(S[0][r], A_, -mn));
            float p1 = exp2f(fmaf(S[1][r], A_, -mn));
            float p2 = exp2f(fmaf(S[2][r], A_, -mn));
            float p3 = exp2f(fmaf(S[3][r], A_, -mn));
            float ps = (p0 + p1) + (p2 + p3);
            ps += __shfl_xor(ps, 1);
            ps += __shfl_xor(ps, 2);
            ps += __shfl_xor(ps, 4);
            ps += __shfl_xor(ps, 8);
            l[r] += ps;
            int row = (l4 << 2) + r;
            Pl[w][row][l15]      = f2b(p0);
            Pl[w][row][16 + l15] = f2b(p1);
            Pl[w][row][32 + l15] = f2b(p2);
            Pl[w][row][48 + l15] = f2b(p3);
        }

        // ---- PV: acc += P[16x64] @ V[64x64] ----
        bf16x8 pa0 = *reinterpret_cast<const bf16x8*>(&Pl[w][l15][l4 * 8]);
        bf16x8 pa1 = *reinterpret_cast<const bf16x8*>(&Pl[w][l15][32 + l4 * 8]);
#pragma unroll
        for (int dg = 0; dg < 4; ++dg) {
            bf16x8 v0 = *reinterpret_cast<const bf16x8*>(&Vts[dg * 16 + l15][l4 * 8]);
            bf16x8 v1 = *reinterpret_cast<const bf16x8*>(&Vts[dg * 16 + l15][32 + l4 * 8]);
            acc[dg] = __builtin_amdgcn_mfma_f32_16x16x32_bf16(pa0, v0, acc[dg], 0, 0, 0);
            acc[dg] = __builtin_amdgcn_mfma_f32_16x16x32_bf16(pa1, v1, acc[dg], 0, 0, 0);
        }
        __syncthreads();
    }

    // ---- epilogue: out_pre = query + acc/l ----
#pragma unroll
    for (int r = 0; r < 4; ++r) {
        float inv = 1.0f / l[r];
        int row = qrow0 + (l4 << 2) + r;
        size_t base = ((size_t)(b * NSEQ) + row) * C_ + h * D_ + l15;
#pragma unroll
        for (int dg = 0; dg < 4; ++dg) {
            out_pre[base + dg * 16] = acc[dg][r] * inv + query[base + dg * 16];
        }
    }
}

// ---------------- launcher ----------------
extern "C" void kernel_launch(void* const* d_in, const int* in_sizes, int n_in,
                              void* d_out, int out_size, void* d_ws, size_t ws_size,
                              hipStream_t stream)
{
    const float* query     = (const float*)d_in[0];
    const float* key_value = (const float*)d_in[1];
    const float* Wq = (const float*)d_in[2];
    const float* bq = (const float*)d_in[3];
    const float* Wk = (const float*)d_in[4];
    const float* bk = (const float*)d_in[5];
    const float* Wv = (const float*)d_in[6];
    const float* bv = (const float*)d_in[7];
    const float* Wo = (const float*)d_in[8];
    const float* bo = (const float*)d_in[9];
    const float* g_q = (const float*)d_in[10];
    const float* be_q = (const float*)d_in[11];
    const float* g_k = (const float*)d_in[12];
    const float* be_k = (const float*)d_in[13];
    const float* g_o = (const float*)d_in[14];
    const float* be_o = (const float*)d_in[15];
    float* out = (float*)d_out;

    float* ws = (float*)d_ws;
    float2* part_q  = (float2*)ws;
    float2* part_kv = part_q + 2 * NBLK_RED;
    float2* part_o  = part_kv + 2 * NBLK_RED;
    float2* stat_q  = part_o + 2 * NBLK_RED;
    float2* stat_kv = stat_q + 2;
    float2* stat_o  = stat_kv + 2;

    const size_t SZ = (size_t)B_ * NFULL;           // 2M floats
    float* big     = ws + 4096;
    float* q_n     = big;
    float* kv_n    = q_n + SZ;
    float* qp      = kv_n + SZ;
    float* kp      = qp + SZ;
    float* vp      = kp + SZ;
    float* out_pre = vp + SZ;
    float* o_n     = out_pre + SZ;

    // bf16 overlays: q_n / kv_n are dead after gemm3_k
    unsigned short* Qb  = (unsigned short*)q_n;                 // 4MB
    unsigned short* KbB = (unsigned short*)(q_n + SZ / 2);      // 4MB
    unsigned short* VtB = (unsigned short*)kv_n;                // 4MB

    dim3 blk(256);

    reduce_partial_k<<<dim3(NBLK_RED, B_), blk, 0, stream>>>(query, part_q);
    reduce_partial_k<<<dim3(NBLK_RED, B_), blk, 0, stream>>>(key_value, part_kv);
    reduce_final_k<<<dim3(B_), blk, 0, stream>>>(part_q, stat_q);
    reduce_final_k<<<dim3(B_), blk, 0, stream>>>(part_kv, stat_kv);
    normalize_k<<<dim3(2048), blk, 0, stream>>>(query, stat_q, g_q, be_q, q_n);
    normalize_k<<<dim3(2048), blk, 0, stream>>>(key_value, stat_kv, g_k, be_k, kv_n);

    gemm3_k<<<dim3(32, 8, 3), blk, 0, stream>>>(q_n, kv_n, Wq, bq, Wk, bk, Wv, bv, qp, kp, vp);

    f32_to_bf16_k<<<dim3(2048), blk, 0, stream>>>(qp, Qb);
    f32_to_bf16_k<<<dim3(2048), blk, 0, stream>>>(kp, KbB);
    transpose_v_k<<<dim3(NSEQ / 64, H_, B_), blk, 0, stream>>>(vp, VtB);

    attn2_k<<<dim3(NSEQ / 64, H_, B_), blk, 0, stream>>>(Qb, KbB, VtB, query, out_pre);

    reduce_partial_k<<<dim3(NBLK_RED, B_), blk, 0, stream>>>(out_pre, part_o);
    reduce_final_k<<<dim3(B_), blk, 0, stream>>>(part_o, stat_o);
    normalize_k<<<dim3(2048), blk, 0, stream>>>(out_pre, stat_o, g_o, be_o, o_n);

    gemm_out_k<<<dim3(32, 8), blk, 0, stream>>>(o_n, Wo, bo, out_pre, out);
}

// Round 4
// 167.827 us; speedup vs baseline: 3.5875x; 1.6065x over previous
//
#include <hip/hip_runtime.h>
#include <cstddef>
#include <cstdint>

// ---------------- problem constants ----------------
#define B_     2
#define NSEQ   2048
#define C_     512
#define H_     8
#define D_     64
#define NFULL  (NSEQ * C_)        // 1048576 elems per batch
#define N4     (NFULL / 4)        // 262144 float4 per batch
#define EPS_   1e-5f
#define LOG2E  1.4426950408889634f
#define RSQRT512 0.044194173824159216f
#define NBLK_RED 256

typedef __attribute__((ext_vector_type(8))) short bf16x8;
typedef __attribute__((ext_vector_type(4))) float f32x4;

__device__ __forceinline__ unsigned short f2b(float x) {
    unsigned int u = __float_as_uint(x);
    u += 0x7FFFu + ((u >> 16) & 1u);          // RNE
    return (unsigned short)(u >> 16);
}
__device__ __forceinline__ float b2f(unsigned short h) {
    return __uint_as_float(((unsigned int)h) << 16);
}

// ---------------- set-norm statistics (deterministic 2-stage) ----------------
__global__ __launch_bounds__(256) void reduce_partial_k(const float* __restrict__ x,
                                                        float2* __restrict__ partials)
{
    int b = blockIdx.y;
    const float4* xb = reinterpret_cast<const float4*>(x + (size_t)b * NFULL);
    int base = blockIdx.x * 1024 + threadIdx.x;
    float s = 0.f, ss = 0.f;
#pragma unroll
    for (int i = 0; i < 4; ++i) {
        float4 v = xb[base + i * 256];
        s  += (v.x + v.y) + (v.z + v.w);
        ss += (v.x * v.x + v.y * v.y) + (v.z * v.z + v.w * v.w);
    }
    __shared__ float rs[256], rss[256];
    rs[threadIdx.x] = s; rss[threadIdx.x] = ss;
    __syncthreads();
    for (int off = 128; off > 0; off >>= 1) {
        if (threadIdx.x < off) {
            rs[threadIdx.x]  += rs[threadIdx.x + off];
            rss[threadIdx.x] += rss[threadIdx.x + off];
        }
        __syncthreads();
    }
    if (threadIdx.x == 0)
        partials[b * NBLK_RED + blockIdx.x] = make_float2(rs[0], rss[0]);
}

__global__ __launch_bounds__(NBLK_RED) void reduce_final_k(const float2* __restrict__ partials,
                                                           float2* __restrict__ stat)
{
    int b = blockIdx.x;
    float2 p = partials[b * NBLK_RED + threadIdx.x];
    __shared__ float rs[256], rss[256];
    rs[threadIdx.x] = p.x; rss[threadIdx.x] = p.y;
    __syncthreads();
    for (int off = 128; off > 0; off >>= 1) {
        if (threadIdx.x < off) {
            rs[threadIdx.x]  += rs[threadIdx.x + off];
            rss[threadIdx.x] += rss[threadIdx.x + off];
        }
        __syncthreads();
    }
    if (threadIdx.x == 0) {
        float mu  = rs[0] / (float)NFULL;
        float var = rss[0] / (float)NFULL - mu * mu;
        stat[b] = make_float2(mu, rsqrtf(var + EPS_));
    }
}

// ---------------- fused normalize -> split bf16 (hi + lo) ----------------
__global__ __launch_bounds__(256) void normalize_split_k(const float* __restrict__ x,
                                                         const float2* __restrict__ stat,
                                                         const float* __restrict__ gamma,
                                                         const float* __restrict__ beta,
                                                         unsigned short* __restrict__ yhi,
                                                         unsigned short* __restrict__ ylo)
{
    int i4 = blockIdx.x * 256 + threadIdx.x;
    int b  = i4 / N4;
    int f4 = i4 & 127;
    float2 st = stat[b];
    float4 v  = reinterpret_cast<const float4*>(x)[i4];
    float4 g  = reinterpret_cast<const float4*>(gamma)[f4];
    float4 be = reinterpret_cast<const float4*>(beta)[f4];
    float r0 = (v.x - st.x) * st.y * g.x + be.x;
    float r1 = (v.y - st.x) * st.y * g.y + be.y;
    float r2 = (v.z - st.x) * st.y * g.z + be.z;
    float r3 = (v.w - st.x) * st.y * g.w + be.w;
    ushort4 hi, lo;
    hi.x = f2b(r0); lo.x = f2b(r0 - b2f(hi.x));
    hi.y = f2b(r1); lo.y = f2b(r1 - b2f(hi.y));
    hi.z = f2b(r2); lo.z = f2b(r2 - b2f(hi.z));
    hi.w = f2b(r3); lo.w = f2b(r3 - b2f(hi.w));
    reinterpret_cast<ushort4*>(yhi)[i4] = hi;
    reinterpret_cast<ushort4*>(ylo)[i4] = lo;
}

// ---------------- weight prep: W[512][512] fp32 -> Wt[n][k] bf16 hi/lo ----------------
__global__ __launch_bounds__(256) void prep_w_k(const float* __restrict__ Wq, const float* __restrict__ Wk,
                                                const float* __restrict__ Wv, const float* __restrict__ Wo,
                                                unsigned short* __restrict__ Wt_hi,
                                                unsigned short* __restrict__ Wt_lo)
{
    __shared__ float T[64][65];
    int z = blockIdx.z;
    const float* W = (z == 0) ? Wq : (z == 1) ? Wk : (z == 2) ? Wv : Wo;
    int k0 = blockIdx.x * 64, n0 = blockIdx.y * 64;
    int tid = threadIdx.x;
#pragma unroll
    for (int i = 0; i < 4; ++i) {
        int idx = tid + i * 256;
        int r = idx >> 4, c4 = (idx & 15) * 4;
        float4 v = *reinterpret_cast<const float4*>(W + (size_t)(k0 + r) * 512 + n0 + c4);
        T[r][c4] = v.x; T[r][c4 + 1] = v.y; T[r][c4 + 2] = v.z; T[r][c4 + 3] = v.w;
    }
    __syncthreads();
#pragma unroll
    for (int i = 0; i < 4; ++i) {
        int idx = tid + i * 256;
        int n = idx >> 4, k4 = (idx & 15) * 4;
        ushort4 hi, lo;
        float x0 = T[k4 + 0][n], x1 = T[k4 + 1][n], x2 = T[k4 + 2][n], x3 = T[k4 + 3][n];
        hi.x = f2b(x0); lo.x = f2b(x0 - b2f(hi.x));
        hi.y = f2b(x1); lo.y = f2b(x1 - b2f(hi.y));
        hi.z = f2b(x2); lo.z = f2b(x2 - b2f(hi.z));
        hi.w = f2b(x3); lo.w = f2b(x3 - b2f(hi.w));
        size_t o = ((size_t)z * 512 + n0 + n) * 512 + k0 + k4;
        *reinterpret_cast<ushort4*>(Wt_hi + o) = hi;
        *reinterpret_cast<ushort4*>(Wt_lo + o) = lo;
    }
}

// ---------------- split-bf16 MFMA GEMM body ----------------
// C[M][512] = A[M][512] @ W[512][512];  A,W given as hi/lo bf16 (A row-major, W transposed [n][k]).
// Block: 256 threads (2x2 waves), tile BM x 128, BK=32. Wave tile: (MI*16) x 64.
// 3 MFMAs per fragment pair: hi*hi + hi*lo + lo*hi  (fp32-grade accuracy).
template<int MI, bool BF16OUT>
__device__ __forceinline__ void gemm_split_body(const unsigned short* __restrict__ Ahi,
                                                const unsigned short* __restrict__ Alo,
                                                const unsigned short* __restrict__ Whi,
                                                const unsigned short* __restrict__ Wlo,
                                                const float* __restrict__ bias,
                                                const float* __restrict__ res,
                                                unsigned short* __restrict__ outb,
                                                float* __restrict__ outf)
{
    constexpr int BM = MI * 32;
    __shared__ unsigned short AH[BM][40], AL[BM][40];
    __shared__ unsigned short BH[128][40], BL[128][40];
    const int tid = threadIdx.x;
    const int w = tid >> 6, lane = tid & 63, l15 = lane & 15, l4 = lane >> 4;
    const int wm = w >> 1, wn = w & 1;
    const int m0 = blockIdx.x * BM, n0 = blockIdx.y * 128;

    f32x4 acc[MI][4];
#pragma unroll
    for (int mi = 0; mi < MI; ++mi)
#pragma unroll
        for (int nj = 0; nj < 4; ++nj) acc[mi][nj] = (f32x4){0.f, 0.f, 0.f, 0.f};

    for (int kt = 0; kt < 512; kt += 32) {
#pragma unroll
        for (int p = 0; p < BM / 64; ++p) {       // A tile: BM x 32
            int f = tid + p * 256;
            int r = f >> 2, c8 = (f & 3) * 8;
            size_t g = (size_t)(m0 + r) * 512 + kt + c8;
            *reinterpret_cast<uint4*>(&AH[r][c8]) = *reinterpret_cast<const uint4*>(Ahi + g);
            *reinterpret_cast<uint4*>(&AL[r][c8]) = *reinterpret_cast<const uint4*>(Alo + g);
        }
#pragma unroll
        for (int p = 0; p < 2; ++p) {             // B tile: 128 x 32
            int f = tid + p * 256;
            int r = f >> 2, c8 = (f & 3) * 8;
            size_t g = (size_t)(n0 + r) * 512 + kt + c8;
            *reinterpret_cast<uint4*>(&BH[r][c8]) = *reinterpret_cast<const uint4*>(Whi + g);
            *reinterpret_cast<uint4*>(&BL[r][c8]) = *reinterpret_cast<const uint4*>(Wlo + g);
        }
        __syncthreads();

        bf16x8 ah[MI], al[MI], bh[4], bl[4];
#pragma unroll
        for (int mi = 0; mi < MI; ++mi) {
            int rr = wm * (MI * 16) + mi * 16 + l15;
            ah[mi] = *reinterpret_cast<const bf16x8*>(&AH[rr][l4 * 8]);
            al[mi] = *reinterpret_cast<const bf16x8*>(&AL[rr][l4 * 8]);
        }
#pragma unroll
        for (int nj = 0; nj < 4; ++nj) {
            int rr = wn * 64 + nj * 16 + l15;
            bh[nj] = *reinterpret_cast<const bf16x8*>(&BH[rr][l4 * 8]);
            bl[nj] = *reinterpret_cast<const bf16x8*>(&BL[rr][l4 * 8]);
        }
#pragma unroll
        for (int mi = 0; mi < MI; ++mi)
#pragma unroll
            for (int nj = 0; nj < 4; ++nj) {
                acc[mi][nj] = __builtin_amdgcn_mfma_f32_16x16x32_bf16(ah[mi], bh[nj], acc[mi][nj], 0, 0, 0);
                acc[mi][nj] = __builtin_amdgcn_mfma_f32_16x16x32_bf16(ah[mi], bl[nj], acc[mi][nj], 0, 0, 0);
                acc[mi][nj] = __builtin_amdgcn_mfma_f32_16x16x32_bf16(al[mi], bh[nj], acc[mi][nj], 0, 0, 0);
            }
        __syncthreads();
    }

#pragma unroll
    for (int nj = 0; nj < 4; ++nj) {
        int col = n0 + wn * 64 + nj * 16 + l15;
        float bv = bias[col];
#pragma unroll
        for (int mi = 0; mi < MI; ++mi) {
#pragma unroll
            for (int r = 0; r < 4; ++r) {
                int row = m0 + wm * (MI * 16) + mi * 16 + l4 * 4 + r;
                size_t off = (size_t)row * 512 + col;
                float c = acc[mi][nj][r] + bv;
                if (BF16OUT) {
                    outb[off] = f2b(c);
                } else {
                    outf[off] = res[off] + fmaxf(c, 0.f);
                }
            }
        }
    }
}

__global__ __launch_bounds__(256) void gemm3_split_k(const unsigned short* __restrict__ qn_hi,
                                                     const unsigned short* __restrict__ qn_lo,
                                                     const unsigned short* __restrict__ kvn_hi,
                                                     const unsigned short* __restrict__ kvn_lo,
                                                     const unsigned short* __restrict__ Wt_hi,
                                                     const unsigned short* __restrict__ Wt_lo,
                                                     const float* __restrict__ bq, const float* __restrict__ bk,
                                                     const float* __restrict__ bv,
                                                     unsigned short* __restrict__ Qb,
                                                     unsigned short* __restrict__ Kb,
                                                     unsigned short* __restrict__ Vb)
{
    int z = blockIdx.z;
    const unsigned short* Ahi = (z == 0) ? qn_hi : kvn_hi;
    const unsigned short* Alo = (z == 0) ? qn_lo : kvn_lo;
    const unsigned short* Whi = Wt_hi + (size_t)z * 512 * 512;
    const unsigned short* Wlo = Wt_lo + (size_t)z * 512 * 512;
    const float* bias = (z == 0) ? bq : (z == 1) ? bk : bv;
    unsigned short* outb = (z == 0) ? Qb : (z == 1) ? Kb : Vb;
    gemm_split_body<4, true>(Ahi, Alo, Whi, Wlo, bias, nullptr, outb, nullptr);
}

__global__ __launch_bounds__(256) void gemm_out_split_k(const unsigned short* __restrict__ on_hi,
                                                        const unsigned short* __restrict__ on_lo,
                                                        const unsigned short* __restrict__ Whi,
                                                        const unsigned short* __restrict__ Wlo,
                                                        const float* __restrict__ bo,
                                                        const float* __restrict__ res,
                                                        float* __restrict__ out)
{
    gemm_split_body<2, false>(on_hi, on_lo, Whi, Wlo, bo, res, nullptr, out);
}

// ---------------- V transpose: Vb[b][n][c] bf16 -> Vt[(b*8+h)*64+d][n] bf16 ----------------
__global__ __launch_bounds__(256) void transpose_v_k(const unsigned short* __restrict__ vb,
                                                     unsigned short* __restrict__ Vt)
{
    __shared__ unsigned short T[64][72];
    int nb = blockIdx.x * 64, h = blockIdx.y, b = blockIdx.z;
    int tid = threadIdx.x;
#pragma unroll
    for (int i = 0; i < 2; ++i) {
        int idx = tid + i * 256;
        int n = idx >> 3, d8 = (idx & 7) * 8;
        *reinterpret_cast<uint4*>(&T[n][d8]) =
            *reinterpret_cast<const uint4*>(vb + (size_t)(b * NSEQ + nb + n) * C_ + h * D_ + d8);
    }
    __syncthreads();
#pragma unroll
    for (int i = 0; i < 4; ++i) {
        int idx = tid + i * 256;
        int d = idx >> 4, n4 = (idx & 15) * 4;
        ushort4 o;
        o.x = T[n4 + 0][d]; o.y = T[n4 + 1][d]; o.z = T[n4 + 2][d]; o.w = T[n4 + 3][d];
        *reinterpret_cast<ushort4*>(Vt + ((size_t)((b * H_ + h) * D_ + d)) * NSEQ + nb + n4) = o;
    }
}

// ---------------- MFMA flash attention ----------------
__global__ __launch_bounds__(256) void attn2_k(const unsigned short* __restrict__ Qb,
                                               const unsigned short* __restrict__ Kb,
                                               const unsigned short* __restrict__ Vt,
                                               const float* __restrict__ query,
                                               float* __restrict__ out_pre)
{
    __shared__ unsigned short Ks[64][72];
    __shared__ unsigned short Vts[64][72];
    __shared__ unsigned short Pl[4][16][72];

    const int tid = threadIdx.x;
    const int w = tid >> 6, lane = tid & 63;
    const int l15 = lane & 15, l4 = lane >> 4;
    const int h = blockIdx.y, b = blockIdx.z;
    const int qrow0 = blockIdx.x * 64 + w * 16;

    const unsigned short* Qbase = Qb + ((size_t)(b * NSEQ + qrow0 + l15)) * C_ + h * D_ + l4 * 8;
    bf16x8 qf0 = *reinterpret_cast<const bf16x8*>(Qbase);
    bf16x8 qf1 = *reinterpret_cast<const bf16x8*>(Qbase + 32);

    f32x4 acc[4];
#pragma unroll
    for (int dg = 0; dg < 4; ++dg) acc[dg] = (f32x4){0.f, 0.f, 0.f, 0.f};
    float m[4], l[4];
#pragma unroll
    for (int r = 0; r < 4; ++r) { m[r] = -3.0e38f; l[r] = 0.f; }

    const float A_ = RSQRT512 * LOG2E;
    const unsigned short* Kbase = Kb + ((size_t)(b * NSEQ)) * C_ + h * D_;
    const unsigned short* Vbase = Vt + ((size_t)((b * H_ + h) * D_)) * NSEQ;

    for (int ch = 0; ch < NSEQ; ch += 64) {
#pragma unroll
        for (int p = 0; p < 2; ++p) {
            int f = tid + p * 256;
            int r0 = f >> 3, g = f & 7;
            uint4 kd = *reinterpret_cast<const uint4*>(Kbase + (size_t)(ch + r0) * C_ + g * 8);
            *reinterpret_cast<uint4*>(&Ks[r0][g * 8]) = kd;
            uint4 vd = *reinterpret_cast<const uint4*>(Vbase + (size_t)r0 * NSEQ + ch + g * 8);
            *reinterpret_cast<uint4*>(&Vts[r0][g * 8]) = vd;
        }
        __syncthreads();

        f32x4 S[4];
#pragma unroll
        for (int kg = 0; kg < 4; ++kg) {
            bf16x8 kb0 = *reinterpret_cast<const bf16x8*>(&Ks[kg * 16 + l15][l4 * 8]);
            bf16x8 kb1 = *reinterpret_cast<const bf16x8*>(&Ks[kg * 16 + l15][32 + l4 * 8]);
            f32x4 s = (f32x4){0.f, 0.f, 0.f, 0.f};
            s = __builtin_amdgcn_mfma_f32_16x16x32_bf16(qf0, kb0, s, 0, 0, 0);
            s = __builtin_amdgcn_mfma_f32_16x16x32_bf16(qf1, kb1, s, 0, 0, 0);
            S[kg] = s;
        }

#pragma unroll
        for (int r = 0; r < 4; ++r) {
            float rm = fmaxf(fmaxf(S[0][r], S[1][r]), fmaxf(S[2][r], S[3][r]));
            rm = fmaxf(rm, __shfl_xor(rm, 1));
            rm = fmaxf(rm, __shfl_xor(rm, 2));
            rm = fmaxf(rm, __shfl_xor(rm, 4));
            rm = fmaxf(rm, __shfl_xor(rm, 8));
            float zr = rm * A_;
            float mn = fmaxf(m[r], zr);
            float c  = exp2f(m[r] - mn);
            m[r] = mn; l[r] *= c;
#pragma unroll
            for (int dg = 0; dg < 4; ++dg) acc[dg][r] *= c;
            float p0 = exp2f(fmaf(S[0][r], A_, -mn));
            float p1 = exp2f(fmaf(S[1][r], A_, -mn));
            float p2 = exp2f(fmaf(S[2][r], A_, -mn));
            float p3 = exp2f(fmaf(S[3][r], A_, -mn));
            float ps = (p0 + p1) + (p2 + p3);
            ps += __shfl_xor(ps, 1);
            ps += __shfl_xor(ps, 2);
            ps += __shfl_xor(ps, 4);
            ps += __shfl_xor(ps, 8);
            l[r] += ps;
            int row = (l4 << 2) + r;
            Pl[w][row][l15]      = f2b(p0);
            Pl[w][row][16 + l15] = f2b(p1);
            Pl[w][row][32 + l15] = f2b(p2);
            Pl[w][row][48 + l15] = f2b(p3);
        }

        bf16x8 pa0 = *reinterpret_cast<const bf16x8*>(&Pl[w][l15][l4 * 8]);
        bf16x8 pa1 = *reinterpret_cast<const bf16x8*>(&Pl[w][l15][32 + l4 * 8]);
#pragma unroll
        for (int dg = 0; dg < 4; ++dg) {
            bf16x8 v0 = *reinterpret_cast<const bf16x8*>(&Vts[dg * 16 + l15][l4 * 8]);
            bf16x8 v1 = *reinterpret_cast<const bf16x8*>(&Vts[dg * 16 + l15][32 + l4 * 8]);
            acc[dg] = __builtin_amdgcn_mfma_f32_16x16x32_bf16(pa0, v0, acc[dg], 0, 0, 0);
            acc[dg] = __builtin_amdgcn_mfma_f32_16x16x32_bf16(pa1, v1, acc[dg], 0, 0, 0);
        }
        __syncthreads();
    }

#pragma unroll
    for (int r = 0; r < 4; ++r) {
        float inv = 1.0f / l[r];
        int row = qrow0 + (l4 << 2) + r;
        size_t base = ((size_t)(b * NSEQ) + row) * C_ + h * D_ + l15;
#pragma unroll
        for (int dg = 0; dg < 4; ++dg) {
            out_pre[base + dg * 16] = acc[dg][r] * inv + query[base + dg * 16];
        }
    }
}

// ---------------- launcher ----------------
extern "C" void kernel_launch(void* const* d_in, const int* in_sizes, int n_in,
                              void* d_out, int out_size, void* d_ws, size_t ws_size,
                              hipStream_t stream)
{
    const float* query     = (const float*)d_in[0];
    const float* key_value = (const float*)d_in[1];
    const float* Wq = (const float*)d_in[2];
    const float* bq = (const float*)d_in[3];
    const float* Wk = (const float*)d_in[4];
    const float* bk = (const float*)d_in[5];
    const float* Wv = (const float*)d_in[6];
    const float* bv = (const float*)d_in[7];
    const float* Wo = (const float*)d_in[8];
    const float* bo = (const float*)d_in[9];
    const float* g_q = (const float*)d_in[10];
    const float* be_q = (const float*)d_in[11];
    const float* g_k = (const float*)d_in[12];
    const float* be_k = (const float*)d_in[13];
    const float* g_o = (const float*)d_in[14];
    const float* be_o = (const float*)d_in[15];
    float* out = (float*)d_out;

    float* ws = (float*)d_ws;
    float2* part_q  = (float2*)ws;
    float2* part_kv = part_q + 2 * NBLK_RED;
    float2* part_o  = part_kv + 2 * NBLK_RED;
    float2* stat_q  = part_o + 2 * NBLK_RED;
    float2* stat_kv = stat_q + 2;
    float2* stat_o  = stat_kv + 2;

    const size_t SZ = (size_t)B_ * NFULL;           // 2,097,152 elements
    char* p = (char*)(ws + 4096);
    unsigned short* qn_hi  = (unsigned short*)p; p += SZ * 2;
    unsigned short* qn_lo  = (unsigned short*)p; p += SZ * 2;
    unsigned short* kvn_hi = (unsigned short*)p; p += SZ * 2;
    unsigned short* kvn_lo = (unsigned short*)p; p += SZ * 2;
    unsigned short* Wt_hi  = (unsigned short*)p; p += (size_t)4 * 512 * 512 * 2;
    unsigned short* Wt_lo  = (unsigned short*)p; p += (size_t)4 * 512 * 512 * 2;
    unsigned short* Qb     = (unsigned short*)p; p += SZ * 2;
    unsigned short* Kb     = (unsigned short*)p; p += SZ * 2;
    unsigned short* Vb     = (unsigned short*)p; p += SZ * 2;
    unsigned short* Vt     = (unsigned short*)p; p += SZ * 2;
    float*          out_pre = (float*)p;         p += SZ * 4;
    unsigned short* on_hi  = (unsigned short*)p; p += SZ * 2;
    unsigned short* on_lo  = (unsigned short*)p; p += SZ * 2;
    // total ~52 MB

    dim3 blk(256);

    prep_w_k<<<dim3(8, 8, 4), blk, 0, stream>>>(Wq, Wk, Wv, Wo, Wt_hi, Wt_lo);

    reduce_partial_k<<<dim3(NBLK_RED, B_), blk, 0, stream>>>(query, part_q);
    reduce_partial_k<<<dim3(NBLK_RED, B_), blk, 0, stream>>>(key_value, part_kv);
    reduce_final_k<<<dim3(B_), blk, 0, stream>>>(part_q, stat_q);
    reduce_final_k<<<dim3(B_), blk, 0, stream>>>(part_kv, stat_kv);
    normalize_split_k<<<dim3(2048), blk, 0, stream>>>(query, stat_q, g_q, be_q, qn_hi, qn_lo);
    normalize_split_k<<<dim3(2048), blk, 0, stream>>>(key_value, stat_kv, g_k, be_k, kvn_hi, kvn_lo);

    gemm3_split_k<<<dim3(32, 4, 3), blk, 0, stream>>>(qn_hi, qn_lo, kvn_hi, kvn_lo,
                                                      Wt_hi, Wt_lo, bq, bk, bv, Qb, Kb, Vb);

    transpose_v_k<<<dim3(NSEQ / 64, H_, B_), blk, 0, stream>>>(Vb, Vt);

    attn2_k<<<dim3(NSEQ / 64, H_, B_), blk, 0, stream>>>(Qb, Kb, Vt, query, out_pre);

    reduce_partial_k<<<dim3(NBLK_RED, B_), blk, 0, stream>>>(out_pre, part_o);
    reduce_final_k<<<dim3(B_), blk, 0, stream>>>(part_o, stat_o);
    normalize_split_k<<<dim3(2048), blk, 0, stream>>>(out_pre, stat_o, g_o, be_o, on_hi, on_lo);

    gemm_out_split_k<<<dim3(64, 4), blk, 0, stream>>>(on_hi, on_lo,
                                                      Wt_hi + (size_t)3 * 512 * 512,
                                                      Wt_lo + (size_t)3 * 512 * 512,
                                                      bo, out_pre, out);
}

// Round 6
// 137.107 us; speedup vs baseline: 4.3914x; 1.2241x over previous
//
#include <hip/hip_runtime.h>
#include <cstddef>
#include <cstdint>

// ---------------- problem constants ----------------
#define B_     2
#define NSEQ   2048
#define C_     512
#define H_     8
#define D_     64
#define NFULL  (NSEQ * C_)        // 1048576 elems per batch
#define N4     (NFULL / 4)        // 262144 float4 per batch
#define EPS_   1e-5f
#define LOG2E  1.4426950408889634f
#define RSQRT512 0.044194173824159216f
#define NBLK_RED 256

typedef __attribute__((ext_vector_type(8))) short bf16x8;
typedef __attribute__((ext_vector_type(4))) float f32x4;

__device__ __forceinline__ unsigned short f2b(float x) {
    unsigned int u = __float_as_uint(x);
    u += 0x7FFFu + ((u >> 16) & 1u);          // RNE
    return (unsigned short)(u >> 16);
}
__device__ __forceinline__ float b2f(unsigned short h) {
    return __uint_as_float(((unsigned int)h) << 16);
}

// ---------------- set-norm statistics (deterministic 2-stage) ----------------
__global__ __launch_bounds__(256) void reduce_partial_k(const float* __restrict__ x,
                                                        float2* __restrict__ partials)
{
    int b = blockIdx.y;
    const float4* xb = reinterpret_cast<const float4*>(x + (size_t)b * NFULL);
    int base = blockIdx.x * 1024 + threadIdx.x;
    float s = 0.f, ss = 0.f;
#pragma unroll
    for (int i = 0; i < 4; ++i) {
        float4 v = xb[base + i * 256];
        s  += (v.x + v.y) + (v.z + v.w);
        ss += (v.x * v.x + v.y * v.y) + (v.z * v.z + v.w * v.w);
    }
    __shared__ float rs[256], rss[256];
    rs[threadIdx.x] = s; rss[threadIdx.x] = ss;
    __syncthreads();
    for (int off = 128; off > 0; off >>= 1) {
        if (threadIdx.x < off) {
            rs[threadIdx.x]  += rs[threadIdx.x + off];
            rss[threadIdx.x] += rss[threadIdx.x + off];
        }
        __syncthreads();
    }
    if (threadIdx.x == 0)
        partials[b * NBLK_RED + blockIdx.x] = make_float2(rs[0], rss[0]);
}

__global__ __launch_bounds__(NBLK_RED) void reduce_final_k(const float2* __restrict__ partials,
                                                           float2* __restrict__ stat)
{
    int b = blockIdx.x;
    float2 p = partials[b * NBLK_RED + threadIdx.x];
    __shared__ float rs[256], rss[256];
    rs[threadIdx.x] = p.x; rss[threadIdx.x] = p.y;
    __syncthreads();
    for (int off = 128; off > 0; off >>= 1) {
        if (threadIdx.x < off) {
            rs[threadIdx.x]  += rs[threadIdx.x + off];
            rss[threadIdx.x] += rss[threadIdx.x + off];
        }
        __syncthreads();
    }
    if (threadIdx.x == 0) {
        float mu  = rs[0] / (float)NFULL;
        float var = rss[0] / (float)NFULL - mu * mu;
        stat[b] = make_float2(mu, rsqrtf(var + EPS_));
    }
}

// ---------------- fused normalize -> split bf16 (hi + lo) ----------------
__global__ __launch_bounds__(256) void normalize_split_k(const float* __restrict__ x,
                                                         const float2* __restrict__ stat,
                                                         const float* __restrict__ gamma,
                                                         const float* __restrict__ beta,
                                                         unsigned short* __restrict__ yhi,
                                                         unsigned short* __restrict__ ylo)
{
    int i4 = blockIdx.x * 256 + threadIdx.x;
    int b  = i4 / N4;
    int f4 = i4 & 127;
    float2 st = stat[b];
    float4 v  = reinterpret_cast<const float4*>(x)[i4];
    float4 g  = reinterpret_cast<const float4*>(gamma)[f4];
    float4 be = reinterpret_cast<const float4*>(beta)[f4];
    float r0 = (v.x - st.x) * st.y * g.x + be.x;
    float r1 = (v.y - st.x) * st.y * g.y + be.y;
    float r2 = (v.z - st.x) * st.y * g.z + be.z;
    float r3 = (v.w - st.x) * st.y * g.w + be.w;
    ushort4 hi, lo;
    hi.x = f2b(r0); lo.x = f2b(r0 - b2f(hi.x));
    hi.y = f2b(r1); lo.y = f2b(r1 - b2f(hi.y));
    hi.z = f2b(r2); lo.z = f2b(r2 - b2f(hi.z));
    hi.w = f2b(r3); lo.w = f2b(r3 - b2f(hi.w));
    reinterpret_cast<ushort4*>(yhi)[i4] = hi;
    reinterpret_cast<ushort4*>(ylo)[i4] = lo;
}

// ---------------- weight prep: W[512][512] fp32 -> Wt[n][k] bf16 hi/lo ----------------
__global__ __launch_bounds__(256) void prep_w_k(const float* __restrict__ Wq, const float* __restrict__ Wk,
                                                const float* __restrict__ Wv, const float* __restrict__ Wo,
                                                unsigned short* __restrict__ Wt_hi,
                                                unsigned short* __restrict__ Wt_lo)
{
    __shared__ float T[64][65];
    int z = blockIdx.z;
    const float* W = (z == 0) ? Wq : (z == 1) ? Wk : (z == 2) ? Wv : Wo;
    int k0 = blockIdx.x * 64, n0 = blockIdx.y * 64;
    int tid = threadIdx.x;
#pragma unroll
    for (int i = 0; i < 4; ++i) {
        int idx = tid + i * 256;
        int r = idx >> 4, c4 = (idx & 15) * 4;
        float4 v = *reinterpret_cast<const float4*>(W + (size_t)(k0 + r) * 512 + n0 + c4);
        T[r][c4] = v.x; T[r][c4 + 1] = v.y; T[r][c4 + 2] = v.z; T[r][c4 + 3] = v.w;
    }
    __syncthreads();
#pragma unroll
    for (int i = 0; i < 4; ++i) {
        int idx = tid + i * 256;
        int n = idx >> 4, k4 = (idx & 15) * 4;
        ushort4 hi, lo;
        float x0 = T[k4 + 0][n], x1 = T[k4 + 1][n], x2 = T[k4 + 2][n], x3 = T[k4 + 3][n];
        hi.x = f2b(x0); lo.x = f2b(x0 - b2f(hi.x));
        hi.y = f2b(x1); lo.y = f2b(x1 - b2f(hi.y));
        hi.z = f2b(x2); lo.z = f2b(x2 - b2f(hi.z));
        hi.w = f2b(x3); lo.w = f2b(x3 - b2f(hi.w));
        size_t o = ((size_t)z * 512 + n0 + n) * 512 + k0 + k4;
        *reinterpret_cast<ushort4*>(Wt_hi + o) = hi;
        *reinterpret_cast<ushort4*>(Wt_lo + o) = lo;
    }
}

// ---------------- split-bf16 MFMA GEMM body ----------------
template<int MI, bool BF16OUT>
__device__ __forceinline__ void gemm_split_body(const unsigned short* __restrict__ Ahi,
                                                const unsigned short* __restrict__ Alo,
                                                const unsigned short* __restrict__ Whi,
                                                const unsigned short* __restrict__ Wlo,
                                                const float* __restrict__ bias,
                                                const float* __restrict__ res,
                                                unsigned short* __restrict__ outb,
                                                float* __restrict__ outf)
{
    constexpr int BM = MI * 32;
    __shared__ unsigned short AH[BM][40], AL[BM][40];
    __shared__ unsigned short BH[128][40], BL[128][40];
    const int tid = threadIdx.x;
    const int w = tid >> 6, lane = tid & 63, l15 = lane & 15, l4 = lane >> 4;
    const int wm = w >> 1, wn = w & 1;
    const int m0 = blockIdx.x * BM, n0 = blockIdx.y * 128;

    f32x4 acc[MI][4];
#pragma unroll
    for (int mi = 0; mi < MI; ++mi)
#pragma unroll
        for (int nj = 0; nj < 4; ++nj) acc[mi][nj] = (f32x4){0.f, 0.f, 0.f, 0.f};

    for (int kt = 0; kt < 512; kt += 32) {
#pragma unroll
        for (int p = 0; p < BM / 64; ++p) {       // A tile: BM x 32
            int f = tid + p * 256;
            int r = f >> 2, c8 = (f & 3) * 8;
            size_t g = (size_t)(m0 + r) * 512 + kt + c8;
            *reinterpret_cast<uint4*>(&AH[r][c8]) = *reinterpret_cast<const uint4*>(Ahi + g);
            *reinterpret_cast<uint4*>(&AL[r][c8]) = *reinterpret_cast<const uint4*>(Alo + g);
        }
#pragma unroll
        for (int p = 0; p < 2; ++p) {             // B tile: 128 x 32
            int f = tid + p * 256;
            int r = f >> 2, c8 = (f & 3) * 8;
            size_t g = (size_t)(n0 + r) * 512 + kt + c8;
            *reinterpret_cast<uint4*>(&BH[r][c8]) = *reinterpret_cast<const uint4*>(Whi + g);
            *reinterpret_cast<uint4*>(&BL[r][c8]) = *reinterpret_cast<const uint4*>(Wlo + g);
        }
        __syncthreads();

        bf16x8 ah[MI], al[MI], bh[4], bl[4];
#pragma unroll
        for (int mi = 0; mi < MI; ++mi) {
            int rr = wm * (MI * 16) + mi * 16 + l15;
            ah[mi] = *reinterpret_cast<const bf16x8*>(&AH[rr][l4 * 8]);
            al[mi] = *reinterpret_cast<const bf16x8*>(&AL[rr][l4 * 8]);
        }
#pragma unroll
        for (int nj = 0; nj < 4; ++nj) {
            int rr = wn * 64 + nj * 16 + l15;
            bh[nj] = *reinterpret_cast<const bf16x8*>(&BH[rr][l4 * 8]);
            bl[nj] = *reinterpret_cast<const bf16x8*>(&BL[rr][l4 * 8]);
        }
#pragma unroll
        for (int mi = 0; mi < MI; ++mi)
#pragma unroll
            for (int nj = 0; nj < 4; ++nj) {
                acc[mi][nj] = __builtin_amdgcn_mfma_f32_16x16x32_bf16(ah[mi], bh[nj], acc[mi][nj], 0, 0, 0);
                acc[mi][nj] = __builtin_amdgcn_mfma_f32_16x16x32_bf16(ah[mi], bl[nj], acc[mi][nj], 0, 0, 0);
                acc[mi][nj] = __builtin_amdgcn_mfma_f32_16x16x32_bf16(al[mi], bh[nj], acc[mi][nj], 0, 0, 0);
            }
        __syncthreads();
    }

#pragma unroll
    for (int nj = 0; nj < 4; ++nj) {
        int col = n0 + wn * 64 + nj * 16 + l15;
        float bv = bias[col];
#pragma unroll
        for (int mi = 0; mi < MI; ++mi) {
#pragma unroll
            for (int r = 0; r < 4; ++r) {
                int row = m0 + wm * (MI * 16) + mi * 16 + l4 * 4 + r;
                size_t off = (size_t)row * 512 + col;
                float c = acc[mi][nj][r] + bv;
                if (BF16OUT) {
                    outb[off] = f2b(c);
                } else {
                    outf[off] = res[off] + fmaxf(c, 0.f);
                }
            }
        }
    }
}

__global__ __launch_bounds__(256) void gemm3_split_k(const unsigned short* __restrict__ qn_hi,
                                                     const unsigned short* __restrict__ qn_lo,
                                                     const unsigned short* __restrict__ kvn_hi,
                                                     const unsigned short* __restrict__ kvn_lo,
                                                     const unsigned short* __restrict__ Wt_hi,
                                                     const unsigned short* __restrict__ Wt_lo,
                                                     const float* __restrict__ bq, const float* __restrict__ bk,
                                                     const float* __restrict__ bv,
                                                     unsigned short* __restrict__ Qb,
                                                     unsigned short* __restrict__ Kb,
                                                     unsigned short* __restrict__ Vb)
{
    int z = blockIdx.z;
    const unsigned short* Ahi = (z == 0) ? qn_hi : kvn_hi;
    const unsigned short* Alo = (z == 0) ? qn_lo : kvn_lo;
    const unsigned short* Whi = Wt_hi + (size_t)z * 512 * 512;
    const unsigned short* Wlo = Wt_lo + (size_t)z * 512 * 512;
    const float* bias = (z == 0) ? bq : (z == 1) ? bk : bv;
    unsigned short* outb = (z == 0) ? Qb : (z == 1) ? Kb : Vb;
    gemm_split_body<4, true>(Ahi, Alo, Whi, Wlo, bias, nullptr, outb, nullptr);
}

__global__ __launch_bounds__(256) void gemm_out_split_k(const unsigned short* __restrict__ on_hi,
                                                        const unsigned short* __restrict__ on_lo,
                                                        const unsigned short* __restrict__ Whi,
                                                        const unsigned short* __restrict__ Wlo,
                                                        const float* __restrict__ bo,
                                                        const float* __restrict__ res,
                                                        float* __restrict__ out)
{
    gemm_split_body<2, false>(on_hi, on_lo, Whi, Wlo, bo, res, nullptr, out);
}

// ---------------- V transpose: Vb[b][n][c] bf16 -> Vt[(b*8+h)*64+d][n] bf16 ----------------
__global__ __launch_bounds__(256) void transpose_v_k(const unsigned short* __restrict__ vb,
                                                     unsigned short* __restrict__ Vt)
{
    __shared__ unsigned short T[64][72];
    int nb = blockIdx.x * 64, h = blockIdx.y, b = blockIdx.z;
    int tid = threadIdx.x;
#pragma unroll
    for (int i = 0; i < 2; ++i) {
        int idx = tid + i * 256;
        int n = idx >> 3, d8 = (idx & 7) * 8;
        *reinterpret_cast<uint4*>(&T[n][d8]) =
            *reinterpret_cast<const uint4*>(vb + (size_t)(b * NSEQ + nb + n) * C_ + h * D_ + d8);
    }
    __syncthreads();
#pragma unroll
    for (int i = 0; i < 4; ++i) {
        int idx = tid + i * 256;
        int d = idx >> 4, n4 = (idx & 15) * 4;
        ushort4 o;
        o.x = T[n4 + 0][d]; o.y = T[n4 + 1][d]; o.z = T[n4 + 2][d]; o.w = T[n4 + 3][d];
        *reinterpret_cast<ushort4*>(Vt + ((size_t)((b * H_ + h) * D_ + d)) * NSEQ + nb + n4) = o;
    }
}

// ---------------- MFMA flash attention, no-max softmax, KV-split x2 ----------------
// grid (NSEQ/64, H, B*2): z = b*2 + split. Each block: 64 q-rows, 1024 keys.
__global__ __launch_bounds__(256) void attn3_k(const unsigned short* __restrict__ Qb,
                                               const unsigned short* __restrict__ Kb,
                                               const unsigned short* __restrict__ Vt,
                                               float* __restrict__ accP,
                                               float* __restrict__ lP)
{
    __shared__ unsigned short Ks[64][72];
    __shared__ unsigned short Vts[64][72];
    __shared__ unsigned short Pl[4][16][72];

    const int tid = threadIdx.x;
    const int w = tid >> 6, lane = tid & 63;
    const int l15 = lane & 15, l4 = lane >> 4;
    const int h = blockIdx.y;
    const int split = blockIdx.z & 1, b = blockIdx.z >> 1;
    const int qrow0 = blockIdx.x * 64 + w * 16;
    const int kv0 = split * 1024;

    const unsigned short* Qbase = Qb + ((size_t)(b * NSEQ + qrow0 + l15)) * C_ + h * D_ + l4 * 8;
    bf16x8 qf0 = *reinterpret_cast<const bf16x8*>(Qbase);
    bf16x8 qf1 = *reinterpret_cast<const bf16x8*>(Qbase + 32);

    f32x4 acc[4];
#pragma unroll
    for (int dg = 0; dg < 4; ++dg) acc[dg] = (f32x4){0.f, 0.f, 0.f, 0.f};
    float lsum[4] = {0.f, 0.f, 0.f, 0.f};

    const float A_ = RSQRT512 * LOG2E;          // softmax in log2 domain, no max shift
    const unsigned short* Kbase = Kb + ((size_t)(b * NSEQ + kv0)) * C_ + h * D_;
    const unsigned short* Vbase = Vt + ((size_t)((b * H_ + h) * D_)) * NSEQ + kv0;

    for (int ch = 0; ch < 1024; ch += 64) {
#pragma unroll
        for (int p = 0; p < 2; ++p) {
            int f = tid + p * 256;
            int r0 = f >> 3, g = f & 7;
            uint4 kd = *reinterpret_cast<const uint4*>(Kbase + (size_t)(ch + r0) * C_ + g * 8);
            *reinterpret_cast<uint4*>(&Ks[r0][g * 8]) = kd;
            uint4 vd = *reinterpret_cast<const uint4*>(Vbase + (size_t)r0 * NSEQ + ch + g * 8);
            *reinterpret_cast<uint4*>(&Vts[r0][g * 8]) = vd;
        }
        __syncthreads();

        // S = Q K^T (16q x 64k per wave)
        f32x4 S[4];
#pragma unroll
        for (int kg = 0; kg < 4; ++kg) {
            bf16x8 kb0 = *reinterpret_cast<const bf16x8*>(&Ks[kg * 16 + l15][l4 * 8]);
            bf16x8 kb1 = *reinterpret_cast<const bf16x8*>(&Ks[kg * 16 + l15][32 + l4 * 8]);
            f32x4 s = (f32x4){0.f, 0.f, 0.f, 0.f};
            s = __builtin_amdgcn_mfma_f32_16x16x32_bf16(qf0, kb0, s, 0, 0, 0);
            s = __builtin_amdgcn_mfma_f32_16x16x32_bf16(qf1, kb1, s, 0, 0, 0);
            S[kg] = s;
        }

        // no-max softmax: p = exp2(s * A_), accumulate l per-lane
#pragma unroll
        for (int r = 0; r < 4; ++r) {
            float p0 = exp2f(S[0][r] * A_);
            float p1 = exp2f(S[1][r] * A_);
            float p2 = exp2f(S[2][r] * A_);
            float p3 = exp2f(S[3][r] * A_);
            lsum[r] += (p0 + p1) + (p2 + p3);
            int row = (l4 << 2) + r;
            Pl[w][row][l15]      = f2b(p0);
            Pl[w][row][16 + l15] = f2b(p1);
            Pl[w][row][32 + l15] = f2b(p2);
            Pl[w][row][48 + l15] = f2b(p3);
        }

        // PV: acc += P[16x64] @ V[64x64]
        bf16x8 pa0 = *reinterpret_cast<const bf16x8*>(&Pl[w][l15][l4 * 8]);
        bf16x8 pa1 = *reinterpret_cast<const bf16x8*>(&Pl[w][l15][32 + l4 * 8]);
#pragma unroll
        for (int dg = 0; dg < 4; ++dg) {
            bf16x8 v0 = *reinterpret_cast<const bf16x8*>(&Vts[dg * 16 + l15][l4 * 8]);
            bf16x8 v1 = *reinterpret_cast<const bf16x8*>(&Vts[dg * 16 + l15][32 + l4 * 8]);
            acc[dg] = __builtin_amdgcn_mfma_f32_16x16x32_bf16(pa0, v0, acc[dg], 0, 0, 0);
            acc[dg] = __builtin_amdgcn_mfma_f32_16x16x32_bf16(pa1, v1, acc[dg], 0, 0, 0);
        }
        __syncthreads();
    }

    // final l reduction (once): rows live on 16-lane groups sharing l4
#pragma unroll
    for (int r = 0; r < 4; ++r) {
        lsum[r] += __shfl_xor(lsum[r], 1);
        lsum[r] += __shfl_xor(lsum[r], 2);
        lsum[r] += __shfl_xor(lsum[r], 4);
        lsum[r] += __shfl_xor(lsum[r], 8);
    }

    float* accOut = accP + (size_t)split * B_ * NFULL;
    float* lOut   = lP + (size_t)split * B_ * H_ * NSEQ;
#pragma unroll
    for (int r = 0; r < 4; ++r) {
        int row = qrow0 + (l4 << 2) + r;
        size_t base = ((size_t)(b * NSEQ) + row) * C_ + h * D_ + l15;
#pragma unroll
        for (int dg = 0; dg < 4; ++dg)
            accOut[base + dg * 16] = acc[dg][r];
        if (l15 == 0)
            lOut[(size_t)(b * H_ + h) * NSEQ + row] = lsum[r];
    }
}

// ---------------- merge splits + residual + out-norm partial stats ----------------
// grid (256, B); each block handles 1024 float4 (256*1024 = N4 exactly).
__global__ __launch_bounds__(256) void merge_fused_k(const float* __restrict__ accP,
                                                     const float* __restrict__ lP,
                                                     const float* __restrict__ query,
                                                     float* __restrict__ out_pre,
                                                     float2* __restrict__ partials)
{
    int b = blockIdx.y;
    const float4* a0 = reinterpret_cast<const float4*>(accP);
    const float4* a1 = reinterpret_cast<const float4*>(accP + (size_t)B_ * NFULL);
    const float* l0 = lP;
    const float* l1 = lP + (size_t)B_ * H_ * NSEQ;
    float s = 0.f, ss = 0.f;
#pragma unroll
    for (int i = 0; i < 4; ++i) {
        int pos = blockIdx.x * 1024 + threadIdx.x + i * 256;   // float4 index within batch
        size_t i4 = (size_t)b * N4 + pos;
        int n = pos >> 7;             // row (128 float4 per row)
        int h = (pos & 127) >> 4;     // head (16 float4 per head)
        size_t li = (size_t)(b * H_ + h) * NSEQ + n;
        float inv = 1.0f / (l0[li] + l1[li]);
        float4 v0 = a0[i4], v1 = a1[i4];
        float4 q4 = reinterpret_cast<const float4*>(query)[i4];
        float4 r;
        r.x = q4.x + (v0.x + v1.x) * inv;
        r.y = q4.y + (v0.y + v1.y) * inv;
        r.z = q4.z + (v0.z + v1.z) * inv;
        r.w = q4.w + (v0.w + v1.w) * inv;
        reinterpret_cast<float4*>(out_pre)[i4] = r;
        s  += (r.x + r.y) + (r.z + r.w);
        ss += (r.x * r.x + r.y * r.y) + (r.z * r.z + r.w * r.w);
    }
    __shared__ float rs[256], rss[256];
    rs[threadIdx.x] = s; rss[threadIdx.x] = ss;
    __syncthreads();
    for (int off = 128; off > 0; off >>= 1) {
        if (threadIdx.x < off) {
            rs[threadIdx.x]  += rs[threadIdx.x + off];
            rss[threadIdx.x] += rss[threadIdx.x + off];
        }
        __syncthreads();
    }
    if (threadIdx.x == 0)
        partials[b * NBLK_RED + blockIdx.x] = make_float2(rs[0], rss[0]);
}

// ---------------- launcher ----------------
extern "C" void kernel_launch(void* const* d_in, const int* in_sizes, int n_in,
                              void* d_out, int out_size, void* d_ws, size_t ws_size,
                              hipStream_t stream)
{
    const float* query     = (const float*)d_in[0];
    const float* key_value = (const float*)d_in[1];
    const float* Wq = (const float*)d_in[2];
    const float* bq = (const float*)d_in[3];
    const float* Wk = (const float*)d_in[4];
    const float* bk = (const float*)d_in[5];
    const float* Wv = (const float*)d_in[6];
    const float* bv = (const float*)d_in[7];
    const float* Wo = (const float*)d_in[8];
    const float* bo = (const float*)d_in[9];
    const float* g_q = (const float*)d_in[10];
    const float* be_q = (const float*)d_in[11];
    const float* g_k = (const float*)d_in[12];
    const float* be_k = (const float*)d_in[13];
    const float* g_o = (const float*)d_in[14];
    const float* be_o = (const float*)d_in[15];
    float* out = (float*)d_out;

    float* ws = (float*)d_ws;
    // header (16384 floats)
    float2* part_q  = (float2*)ws;                       // 512 f2
    float2* part_kv = part_q + 2 * NBLK_RED;             // 512 f2
    float2* part_o  = part_kv + 2 * NBLK_RED;            // 512 f2
    float2* stat_q  = part_o + 2 * NBLK_RED;
    float2* stat_kv = stat_q + 2;
    float2* stat_o  = stat_kv + 2;

    const size_t SZ = (size_t)B_ * NFULL;                // 2,097,152 elements
    char* p = (char*)(ws + 16384);
    unsigned short* qn_hi  = (unsigned short*)p; p += SZ * 2;
    unsigned short* qn_lo  = (unsigned short*)p; p += SZ * 2;
    unsigned short* kvn_hi = (unsigned short*)p; p += SZ * 2;
    unsigned short* kvn_lo = (unsigned short*)p; p += SZ * 2;
    unsigned short* Wt_hi  = (unsigned short*)p; p += (size_t)4 * 512 * 512 * 2;
    unsigned short* Wt_lo  = (unsigned short*)p; p += (size_t)4 * 512 * 512 * 2;
    unsigned short* Qb     = (unsigned short*)p; p += SZ * 2;
    unsigned short* Kb     = (unsigned short*)p; p += SZ * 2;
    unsigned short* Vb     = (unsigned short*)p; p += SZ * 2;
    unsigned short* Vt     = (unsigned short*)p; p += SZ * 2;
    float*          out_pre = (float*)p;         p += SZ * 4;
    unsigned short* on_hi  = (unsigned short*)p; p += SZ * 2;
    unsigned short* on_lo  = (unsigned short*)p; p += SZ * 2;

    // overlays for attention partials (qn_*/kvn_* dead after gemm3; Vb dead after transpose)
    float* accP = (float*)qn_hi;     // 2 splits x 8MB = 16MB (spans qn_hi..kvn_lo exactly)
    float* lP   = (float*)Vb;        // 2 x 2 x 8 x 2048 x 4B = 256KB (Vb is 4MB)

    dim3 blk(256);

    prep_w_k<<<dim3(8, 8, 4), blk, 0, stream>>>(Wq, Wk, Wv, Wo, Wt_hi, Wt_lo);

    reduce_partial_k<<<dim3(NBLK_RED, B_), blk, 0, stream>>>(query, part_q);
    reduce_partial_k<<<dim3(NBLK_RED, B_), blk, 0, stream>>>(key_value, part_kv);
    reduce_final_k<<<dim3(B_), blk, 0, stream>>>(part_q, stat_q);
    reduce_final_k<<<dim3(B_), blk, 0, stream>>>(part_kv, stat_kv);
    normalize_split_k<<<dim3(2048), blk, 0, stream>>>(query, stat_q, g_q, be_q, qn_hi, qn_lo);
    normalize_split_k<<<dim3(2048), blk, 0, stream>>>(key_value, stat_kv, g_k, be_k, kvn_hi, kvn_lo);

    gemm3_split_k<<<dim3(32, 4, 3), blk, 0, stream>>>(qn_hi, qn_lo, kvn_hi, kvn_lo,
                                                      Wt_hi, Wt_lo, bq, bk, bv, Qb, Kb, Vb);

    transpose_v_k<<<dim3(NSEQ / 64, H_, B_), blk, 0, stream>>>(Vb, Vt);

    attn3_k<<<dim3(NSEQ / 64, H_, B_ * 2), blk, 0, stream>>>(Qb, Kb, Vt, accP, lP);

    merge_fused_k<<<dim3(NBLK_RED, B_), blk, 0, stream>>>(accP, lP, query, out_pre, part_o);
    reduce_final_k<<<dim3(B_), blk, 0, stream>>>(part_o, stat_o);

    normalize_split_k<<<dim3(2048), blk, 0, stream>>>(out_pre, stat_o, g_o, be_o, on_hi, on_lo);

    gemm_out_split_k<<<dim3(64, 4), blk, 0, stream>>>(on_hi, on_lo,
                                                      Wt_hi + (size_t)3 * 512 * 512,
                                                      Wt_lo + (size_t)3 * 512 * 512,
                                                      bo, out_pre, out);
}

// Round 7
// 124.811 us; speedup vs baseline: 4.8240x; 1.0985x over previous
//
#include <hip/hip_runtime.h>
#include <cstddef>
#include <cstdint>

// ---------------- problem constants ----------------
#define B_     2
#define NSEQ   2048
#define C_     512
#define H_     8
#define D_     64
#define NFULL  (NSEQ * C_)        // 1048576 elems per batch
#define N4     (NFULL / 4)        // 262144 float4 per batch
#define EPS_   1e-5f
#define LOG2E  1.4426950408889634f
#define RSQRT512 0.044194173824159216f
#define ASCL   (RSQRT512 * LOG2E)
#define NBLK_RED 256

typedef __attribute__((ext_vector_type(8)))  short bf16x8;
typedef __attribute__((ext_vector_type(4)))  float f32x4;
typedef __attribute__((ext_vector_type(16))) float f32x16;
typedef __attribute__((ext_vector_type(4)))  unsigned int u32x4;

__device__ __forceinline__ unsigned short f2b(float x) {
    unsigned int u = __float_as_uint(x);
    u += 0x7FFFu + ((u >> 16) & 1u);          // RNE
    return (unsigned short)(u >> 16);
}
__device__ __forceinline__ float b2f(unsigned short h) {
    return __uint_as_float(((unsigned int)h) << 16);
}

// ---------------- set-norm partial stats (q & kv fused) ----------------
__global__ __launch_bounds__(256) void reduce_partial_both_k(const float* __restrict__ query,
                                                             const float* __restrict__ key_value,
                                                             float2* __restrict__ part_q,
                                                             float2* __restrict__ part_kv)
{
    const float* x = blockIdx.z ? key_value : query;
    float2* partials = blockIdx.z ? part_kv : part_q;
    int b = blockIdx.y;
    const float4* xb = reinterpret_cast<const float4*>(x + (size_t)b * NFULL);
    int base = blockIdx.x * 1024 + threadIdx.x;
    float s = 0.f, ss = 0.f;
#pragma unroll
    for (int i = 0; i < 4; ++i) {
        float4 v = xb[base + i * 256];
        s  += (v.x + v.y) + (v.z + v.w);
        ss += (v.x * v.x + v.y * v.y) + (v.z * v.z + v.w * v.w);
    }
    __shared__ float rs[256], rss[256];
    rs[threadIdx.x] = s; rss[threadIdx.x] = ss;
    __syncthreads();
    for (int off = 128; off > 0; off >>= 1) {
        if (threadIdx.x < off) {
            rs[threadIdx.x]  += rs[threadIdx.x + off];
            rss[threadIdx.x] += rss[threadIdx.x + off];
        }
        __syncthreads();
    }
    if (threadIdx.x == 0)
        partials[b * NBLK_RED + blockIdx.x] = make_float2(rs[0], rss[0]);
}

// ---------------- normalize (inline final stat reduce) -> split bf16 ----------------
__device__ __forceinline__ void normalize_body(const float* __restrict__ x,
                                               const float2* __restrict__ partials,
                                               const float* __restrict__ gamma,
                                               const float* __restrict__ beta,
                                               unsigned short* __restrict__ yhi,
                                               unsigned short* __restrict__ ylo)
{
    __shared__ float rs[256], rss[256];
    __shared__ float2 stt;
    int tid = threadIdx.x;
    int i4 = blockIdx.x * 256 + tid;
    int b  = i4 / N4;
    float2 pp = partials[b * NBLK_RED + tid];
    rs[tid] = pp.x; rss[tid] = pp.y;
    __syncthreads();
    for (int off = 128; off > 0; off >>= 1) {
        if (tid < off) { rs[tid] += rs[tid + off]; rss[tid] += rss[tid + off]; }
        __syncthreads();
    }
    if (tid == 0) {
        float mu  = rs[0] / (float)NFULL;
        float var = rss[0] / (float)NFULL - mu * mu;
        stt = make_float2(mu, rsqrtf(var + EPS_));
    }
    __syncthreads();
    float2 st = stt;
    int f4 = i4 & 127;
    float4 v  = reinterpret_cast<const float4*>(x)[i4];
    float4 g  = reinterpret_cast<const float4*>(gamma)[f4];
    float4 be = reinterpret_cast<const float4*>(beta)[f4];
    float r0 = (v.x - st.x) * st.y * g.x + be.x;
    float r1 = (v.y - st.x) * st.y * g.y + be.y;
    float r2 = (v.z - st.x) * st.y * g.z + be.z;
    float r3 = (v.w - st.x) * st.y * g.w + be.w;
    ushort4 hi, lo;
    hi.x = f2b(r0); lo.x = f2b(r0 - b2f(hi.x));
    hi.y = f2b(r1); lo.y = f2b(r1 - b2f(hi.y));
    hi.z = f2b(r2); lo.z = f2b(r2 - b2f(hi.z));
    hi.w = f2b(r3); lo.w = f2b(r3 - b2f(hi.w));
    reinterpret_cast<ushort4*>(yhi)[i4] = hi;
    reinterpret_cast<ushort4*>(ylo)[i4] = lo;
}

__global__ __launch_bounds__(256) void normalize_qkv_k(const float* __restrict__ query,
                                                       const float* __restrict__ key_value,
                                                       const float2* __restrict__ part_q,
                                                       const float2* __restrict__ part_kv,
                                                       const float* __restrict__ g_q, const float* __restrict__ be_q,
                                                       const float* __restrict__ g_k, const float* __restrict__ be_k,
                                                       unsigned short* __restrict__ qhi, unsigned short* __restrict__ qlo,
                                                       unsigned short* __restrict__ khi, unsigned short* __restrict__ klo)
{
    int t = blockIdx.y;
    normalize_body(t ? key_value : query, t ? part_kv : part_q,
                   t ? g_k : g_q, t ? be_k : be_q,
                   t ? khi : qhi, t ? klo : qlo);
}

__global__ __launch_bounds__(256) void normalize_inl_k(const float* __restrict__ x,
                                                       const float2* __restrict__ partials,
                                                       const float* __restrict__ gamma,
                                                       const float* __restrict__ beta,
                                                       unsigned short* __restrict__ yhi,
                                                       unsigned short* __restrict__ ylo)
{
    normalize_body(x, partials, gamma, beta, yhi, ylo);
}

// ---------------- weight prep: W[512][512] fp32 -> Wt[n][k] bf16 hi/lo ----------------
__global__ __launch_bounds__(256) void prep_w_k(const float* __restrict__ Wq, const float* __restrict__ Wk,
                                                const float* __restrict__ Wv, const float* __restrict__ Wo,
                                                unsigned short* __restrict__ Wt_hi,
                                                unsigned short* __restrict__ Wt_lo)
{
    __shared__ float T[64][65];
    int z = blockIdx.z;
    const float* W = (z == 0) ? Wq : (z == 1) ? Wk : (z == 2) ? Wv : Wo;
    int k0 = blockIdx.x * 64, n0 = blockIdx.y * 64;
    int tid = threadIdx.x;
#pragma unroll
    for (int i = 0; i < 4; ++i) {
        int idx = tid + i * 256;
        int r = idx >> 4, c4 = (idx & 15) * 4;
        float4 v = *reinterpret_cast<const float4*>(W + (size_t)(k0 + r) * 512 + n0 + c4);
        T[r][c4] = v.x; T[r][c4 + 1] = v.y; T[r][c4 + 2] = v.z; T[r][c4 + 3] = v.w;
    }
    __syncthreads();
#pragma unroll
    for (int i = 0; i < 4; ++i) {
        int idx = tid + i * 256;
        int n = idx >> 4, k4 = (idx & 15) * 4;
        ushort4 hi, lo;
        float x0 = T[k4 + 0][n], x1 = T[k4 + 1][n], x2 = T[k4 + 2][n], x3 = T[k4 + 3][n];
        hi.x = f2b(x0); lo.x = f2b(x0 - b2f(hi.x));
        hi.y = f2b(x1); lo.y = f2b(x1 - b2f(hi.y));
        hi.z = f2b(x2); lo.z = f2b(x2 - b2f(hi.z));
        hi.w = f2b(x3); lo.w = f2b(x3 - b2f(hi.w));
        size_t o = ((size_t)z * 512 + n0 + n) * 512 + k0 + k4;
        *reinterpret_cast<ushort4*>(Wt_hi + o) = hi;
        *reinterpret_cast<ushort4*>(Wt_lo + o) = lo;
    }
}

// ---------------- split-bf16 MFMA GEMM body ----------------
// MODE via F32OUT/zmode: F32OUT -> res + relu (fp32 out); else zmode==2 -> transposed Vt
// scatter write; else bf16 out with scale (softmax scale folded into Q).
template<int MI, bool F32OUT>
__device__ __forceinline__ void gemm_split_body(const unsigned short* __restrict__ Ahi,
                                                const unsigned short* __restrict__ Alo,
                                                const unsigned short* __restrict__ Whi,
                                                const unsigned short* __restrict__ Wlo,
                                                const float* __restrict__ bias,
                                                const float* __restrict__ res,
                                                unsigned short* __restrict__ outb,
                                                float* __restrict__ outf,
                                                unsigned short* __restrict__ VtOut,
                                                float scale, int zmode)
{
    constexpr int BM = MI * 32;
    __shared__ unsigned short AH[BM][40], AL[BM][40];
    __shared__ unsigned short BH[128][40], BL[128][40];
    const int tid = threadIdx.x;
    const int w = tid >> 6, lane = tid & 63, l15 = lane & 15, l4 = lane >> 4;
    const int wm = w >> 1, wn = w & 1;
    const int m0 = blockIdx.x * BM, n0 = blockIdx.y * 128;

    f32x4 acc[MI][4];
#pragma unroll
    for (int mi = 0; mi < MI; ++mi)
#pragma unroll
        for (int nj = 0; nj < 4; ++nj) acc[mi][nj] = (f32x4){0.f, 0.f, 0.f, 0.f};

    for (int kt = 0; kt < 512; kt += 32) {
#pragma unroll
        for (int p = 0; p < BM / 64; ++p) {
            int f = tid + p * 256;
            int r = f >> 2, c8 = (f & 3) * 8;
            size_t g = (size_t)(m0 + r) * 512 + kt + c8;
            *reinterpret_cast<uint4*>(&AH[r][c8]) = *reinterpret_cast<const uint4*>(Ahi + g);
            *reinterpret_cast<uint4*>(&AL[r][c8]) = *reinterpret_cast<const uint4*>(Alo + g);
        }
#pragma unroll
        for (int p = 0; p < 2; ++p) {
            int f = tid + p * 256;
            int r = f >> 2, c8 = (f & 3) * 8;
            size_t g = (size_t)(n0 + r) * 512 + kt + c8;
            *reinterpret_cast<uint4*>(&BH[r][c8]) = *reinterpret_cast<const uint4*>(Whi + g);
            *reinterpret_cast<uint4*>(&BL[r][c8]) = *reinterpret_cast<const uint4*>(Wlo + g);
        }
        __syncthreads();

        bf16x8 ah[MI], al[MI], bh[4], bl[4];
#pragma unroll
        for (int mi = 0; mi < MI; ++mi) {
            int rr = wm * (MI * 16) + mi * 16 + l15;
            ah[mi] = *reinterpret_cast<const bf16x8*>(&AH[rr][l4 * 8]);
            al[mi] = *reinterpret_cast<const bf16x8*>(&AL[rr][l4 * 8]);
        }
#pragma unroll
        for (int nj = 0; nj < 4; ++nj) {
            int rr = wn * 64 + nj * 16 + l15;
            bh[nj] = *reinterpret_cast<const bf16x8*>(&BH[rr][l4 * 8]);
            bl[nj] = *reinterpret_cast<const bf16x8*>(&BL[rr][l4 * 8]);
        }
#pragma unroll
        for (int mi = 0; mi < MI; ++mi)
#pragma unroll
            for (int nj = 0; nj < 4; ++nj) {
                acc[mi][nj] = __builtin_amdgcn_mfma_f32_16x16x32_bf16(ah[mi], bh[nj], acc[mi][nj], 0, 0, 0);
                acc[mi][nj] = __builtin_amdgcn_mfma_f32_16x16x32_bf16(ah[mi], bl[nj], acc[mi][nj], 0, 0, 0);
                acc[mi][nj] = __builtin_amdgcn_mfma_f32_16x16x32_bf16(al[mi], bh[nj], acc[mi][nj], 0, 0, 0);
            }
        __syncthreads();
    }

#pragma unroll
    for (int nj = 0; nj < 4; ++nj) {
        int col = n0 + wn * 64 + nj * 16 + l15;
        float bv = bias[col];
#pragma unroll
        for (int mi = 0; mi < MI; ++mi) {
#pragma unroll
            for (int r = 0; r < 4; ++r) {
                int row = m0 + wm * (MI * 16) + mi * 16 + l4 * 4 + r;
                size_t off = (size_t)row * 512 + col;
                float c = acc[mi][nj][r] + bv;
                if (F32OUT) {
                    outf[off] = res[off] + fmaxf(c, 0.f);
                } else if (zmode == 2) {
                    int hh = col >> 6, d = col & 63, bb = row >> 11, n = row & 2047;
                    VtOut[((size_t)((bb * H_ + hh) * D_ + d)) * NSEQ + n] = f2b(c);
                } else {
                    outb[off] = f2b(c * scale);
                }
            }
        }
    }
}

__global__ __launch_bounds__(256) void gemm3_split_k(const unsigned short* __restrict__ qn_hi,
                                                     const unsigned short* __restrict__ qn_lo,
                                                     const unsigned short* __restrict__ kvn_hi,
                                                     const unsigned short* __restrict__ kvn_lo,
                                                     const unsigned short* __restrict__ Wt_hi,
                                                     const unsigned short* __restrict__ Wt_lo,
                                                     const float* __restrict__ bq, const float* __restrict__ bk,
                                                     const float* __restrict__ bv,
                                                     unsigned short* __restrict__ Qb,
                                                     unsigned short* __restrict__ Kb,
                                                     unsigned short* __restrict__ Vt)
{
    int z = blockIdx.z;
    const unsigned short* Ahi = (z == 0) ? qn_hi : kvn_hi;
    const unsigned short* Alo = (z == 0) ? qn_lo : kvn_lo;
    const unsigned short* Whi = Wt_hi + (size_t)z * 512 * 512;
    const unsigned short* Wlo = Wt_lo + (size_t)z * 512 * 512;
    const float* bias = (z == 0) ? bq : (z == 1) ? bk : bv;
    unsigned short* outb = (z == 0) ? Qb : Kb;
    float scale = (z == 0) ? (float)ASCL : 1.0f;   // fold softmax scale (incl. log2e) into Q
    gemm_split_body<4, false>(Ahi, Alo, Whi, Wlo, bias, nullptr, outb, nullptr, Vt, scale, z);
}

__global__ __launch_bounds__(256) void gemm_out_split_k(const unsigned short* __restrict__ on_hi,
                                                        const unsigned short* __restrict__ on_lo,
                                                        const unsigned short* __restrict__ Whi,
                                                        const unsigned short* __restrict__ Wlo,
                                                        const float* __restrict__ bo,
                                                        const float* __restrict__ res,
                                                        float* __restrict__ out)
{
    gemm_split_body<2, true>(on_hi, on_lo, Whi, Wlo, bo, res, nullptr, out, nullptr, 1.0f, 0);
}

// ---------------- MFMA flash attention: 32x32 shape, 1 wave/block, 64 q-rows ----------------
// Swapped QK^T (S^T = mfma(K,Q)); P->A-frag via v_cvt_pk_bf16_f32 + v_permlane32_swap_b32
// (no P LDS). K/V staged in XOR-swizzled LDS (rows 128B, byte ^= (row&7)<<4).
// grid (NSEQ/64, H, B*4): z = b*4 + split; split covers 512 keys (8 chunks of 64).
__global__ __launch_bounds__(64, 2) void attn4_k(const unsigned short* __restrict__ Qb,
                                                 const unsigned short* __restrict__ Kb,
                                                 const unsigned short* __restrict__ Vt,
                                                 float* __restrict__ accS0, float* __restrict__ accS1,
                                                 float* __restrict__ accS2, float* __restrict__ accS3,
                                                 float* __restrict__ lP)
{
    __shared__ uint4 KsB[512];          // 8KB: [64 keys][64 d] bf16, swizzled
    __shared__ uint4 VsB[512];          // 8KB: [64 d][64 keys] bf16, swizzled
    char* Ks = (char*)KsB;
    char* Vs = (char*)VsB;

    const int lane = threadIdx.x;
    const int l31 = lane & 31, hi = lane >> 5;
    const int h = blockIdx.y;
    const int b = blockIdx.z >> 2, split = blockIdx.z & 3;
    const int qrow0 = blockIdx.x * 64;
    const int kv0 = split * 512;

    // Q B-frags (col=q=l31, k=d = ds*16 + hi*8 + j); Q pre-scaled by ASCL
    bf16x8 qf[2][4];
#pragma unroll
    for (int qg = 0; qg < 2; ++qg)
#pragma unroll
        for (int ds = 0; ds < 4; ++ds)
            qf[qg][ds] = *reinterpret_cast<const bf16x8*>(
                Qb + ((size_t)(b * NSEQ + qrow0 + qg * 32 + l31)) * C_ + h * D_ + ds * 16 + hi * 8);

    f32x16 acc[2][2];                   // [qg][dh]; C: col=d=l31, row=(rg&3)+8*(rg>>2)+4*hi
#pragma unroll
    for (int qg = 0; qg < 2; ++qg)
#pragma unroll
        for (int dh = 0; dh < 2; ++dh)
#pragma unroll
            for (int rg = 0; rg < 16; ++rg) acc[qg][dh][rg] = 0.f;
    float lsum[2] = {0.f, 0.f};

    const unsigned short* Kg = Kb + ((size_t)(b * NSEQ + kv0)) * C_ + h * D_;
    const unsigned short* Vg = Vt + ((size_t)((b * H_ + h) * D_)) * NSEQ + kv0;
    const int r8 = lane >> 3, g8 = lane & 7;

    for (int ch = 0; ch < 512; ch += 64) {
        // ---- stage K chunk [64k][64d] + V chunk [64d][64k], swizzled ----
#pragma unroll
        for (int c = 0; c < 8; ++c) {
            int row = c * 8 + r8;
            int sg = g8 ^ (row & 7);
            uint4 kd = *reinterpret_cast<const uint4*>(Kg + (size_t)(ch + row) * C_ + g8 * 8);
            *reinterpret_cast<uint4*>(Ks + row * 128 + sg * 16) = kd;
            uint4 vd = *reinterpret_cast<const uint4*>(Vg + (size_t)row * NSEQ + ch + g8 * 8);
            *reinterpret_cast<uint4*>(Vs + row * 128 + sg * 16) = vd;
        }
        // single wave: DS ops are in-order per wave; compiler inserts data-dep waits.

#pragma unroll
        for (int kg = 0; kg < 2; ++kg) {
            // K A-frags: row=key=kg*32+l31, k=d
            bf16x8 kf[4];
#pragma unroll
            for (int ds = 0; ds < 4; ++ds) {
                int row = kg * 32 + l31;
                kf[ds] = *reinterpret_cast<const bf16x8*>(
                    Ks + row * 128 + ((ds * 32 + hi * 16) ^ ((row & 7) << 4)));
            }
            // V B-frags: col=d=l31(+dh*32), k=key = (kg*2+st)*16 + hi*8 + j
            bf16x8 vf[2][2];
#pragma unroll
            for (int dh = 0; dh < 2; ++dh)
#pragma unroll
                for (int st = 0; st < 2; ++st) {
                    int row = dh * 32 + l31;
                    int ks = kg * 2 + st;
                    vf[dh][st] = *reinterpret_cast<const bf16x8*>(
                        Vs + row * 128 + ((ks * 32 + hi * 16) ^ ((row & 7) << 4)));
                }
#pragma unroll
            for (int qg = 0; qg < 2; ++qg) {
                // S^T[key][q] for 32 keys x 32 q
                f32x16 S;
#pragma unroll
                for (int rg = 0; rg < 16; ++rg) S[rg] = 0.f;
#pragma unroll
                for (int ds = 0; ds < 4; ++ds)
                    S = __builtin_amdgcn_mfma_f32_32x32x16_bf16(kf[ds], qf[qg][ds], S, 0, 0, 0);

                // p = exp2(S) (scale folded into Q); denominators
                float p[16];
#pragma unroll
                for (int rg = 0; rg < 16; ++rg) p[rg] = exp2f(S[rg]);
                float ls = ((p[0] + p[1]) + (p[2] + p[3])) + ((p[4] + p[5]) + (p[6] + p[7]))
                         + ((p[8] + p[9]) + (p[10] + p[11])) + ((p[12] + p[13]) + (p[14] + p[15]));
                lsum[qg] += ls;

                // pack to bf16 pairs; reg r holds key (r&3)+8*(r>>2)+4*hi (+kg*32)
                unsigned pk[8];
#pragma unroll
                for (int kk = 0; kk < 8; ++kk)
                    asm("v_cvt_pk_bf16_f32 %0, %1, %2" : "=v"(pk[kk]) : "v"(p[2 * kk]), "v"(p[2 * kk + 1]));
                // cross-half exchange: after swap(a,b): a={a.lo,b.lo}, b={a.hi,b.hi}
                asm("v_permlane32_swap_b32 %0, %1" : "+v"(pk[0]), "+v"(pk[2]));
                asm("v_permlane32_swap_b32 %0, %1" : "+v"(pk[1]), "+v"(pk[3]));
                asm("v_permlane32_swap_b32 %0, %1" : "+v"(pk[4]), "+v"(pk[6]));
                asm("v_permlane32_swap_b32 %0, %1" : "+v"(pk[5]), "+v"(pk[7]));
                bf16x8 pa0 = __builtin_bit_cast(bf16x8, (u32x4){pk[0], pk[1], pk[2], pk[3]});
                bf16x8 pa1 = __builtin_bit_cast(bf16x8, (u32x4){pk[4], pk[5], pk[6], pk[7]});

                // PV: acc[qg][dh] += P[32q x 32k] @ V[32k x 32d]
#pragma unroll
                for (int dh = 0; dh < 2; ++dh) {
                    acc[qg][dh] = __builtin_amdgcn_mfma_f32_32x32x16_bf16(pa0, vf[dh][0], acc[qg][dh], 0, 0, 0);
                    acc[qg][dh] = __builtin_amdgcn_mfma_f32_32x32x16_bf16(pa1, vf[dh][1], acc[qg][dh], 0, 0, 0);
                }
            }
        }
    }

    // reduce denominators across lane halves (q lives on l31, both hi halves hold partials)
#pragma unroll
    for (int qg = 0; qg < 2; ++qg) lsum[qg] += __shfl_xor(lsum[qg], 32);

    float* accOut = (split == 0) ? accS0 : (split == 1) ? accS1 : (split == 2) ? accS2 : accS3;
    float* lOut = lP + (size_t)split * (B_ * H_ * NSEQ);
#pragma unroll
    for (int qg = 0; qg < 2; ++qg) {
#pragma unroll
        for (int dh = 0; dh < 2; ++dh)
#pragma unroll
            for (int rg = 0; rg < 16; ++rg) {
                int q = qrow0 + qg * 32 + (rg & 3) + 8 * (rg >> 2) + 4 * hi;
                accOut[((size_t)(b * NSEQ + q)) * C_ + h * D_ + dh * 32 + l31] = acc[qg][dh][rg];
            }
        if (lane < 32)
            lOut[(size_t)(b * H_ + h) * NSEQ + qrow0 + qg * 32 + lane] = lsum[qg];
    }
}

// ---------------- merge 4 splits + residual + out-norm partial stats ----------------
__global__ __launch_bounds__(256) void merge4_k(const float* __restrict__ a0, const float* __restrict__ a1,
                                                const float* __restrict__ a2, const float* __restrict__ a3,
                                                const float* __restrict__ lP,
                                                const float* __restrict__ query,
                                                float* __restrict__ out_pre,
                                                float2* __restrict__ partials)
{
    int b = blockIdx.y;
    const int LS = B_ * H_ * NSEQ;
    float s = 0.f, ss = 0.f;
#pragma unroll
    for (int i = 0; i < 4; ++i) {
        int pos = blockIdx.x * 1024 + threadIdx.x + i * 256;
        size_t i4 = (size_t)b * N4 + pos;
        int n = pos >> 7;
        int hh = (pos & 127) >> 4;
        size_t li = (size_t)(b * H_ + hh) * NSEQ + n;
        float inv = 1.0f / (((lP[li] + lP[LS + li]) + (lP[2 * LS + li] + lP[3 * LS + li])));
        float4 v0 = reinterpret_cast<const float4*>(a0)[i4];
        float4 v1 = reinterpret_cast<const float4*>(a1)[i4];
        float4 v2 = reinterpret_cast<const float4*>(a2)[i4];
        float4 v3 = reinterpret_cast<const float4*>(a3)[i4];
        float4 q4 = reinterpret_cast<const float4*>(query)[i4];
        float4 r;
        r.x = q4.x + ((v0.x + v1.x) + (v2.x + v3.x)) * inv;
        r.y = q4.y + ((v0.y + v1.y) + (v2.y + v3.y)) * inv;
        r.z = q4.z + ((v0.z + v1.z) + (v2.z + v3.z)) * inv;
        r.w = q4.w + ((v0.w + v1.w) + (v2.w + v3.w)) * inv;
        reinterpret_cast<float4*>(out_pre)[i4] = r;
        s  += (r.x + r.y) + (r.z + r.w);
        ss += (r.x * r.x + r.y * r.y) + (r.z * r.z + r.w * r.w);
    }
    __shared__ float rs[256], rss[256];
    rs[threadIdx.x] = s; rss[threadIdx.x] = ss;
    __syncthreads();
    for (int off = 128; off > 0; off >>= 1) {
        if (threadIdx.x < off) {
            rs[threadIdx.x]  += rs[threadIdx.x + off];
            rss[threadIdx.x] += rss[threadIdx.x + off];
        }
        __syncthreads();
    }
    if (threadIdx.x == 0)
        partials[b * NBLK_RED + blockIdx.x] = make_float2(rs[0], rss[0]);
}

// ---------------- launcher ----------------
extern "C" void kernel_launch(void* const* d_in, const int* in_sizes, int n_in,
                              void* d_out, int out_size, void* d_ws, size_t ws_size,
                              hipStream_t stream)
{
    const float* query     = (const float*)d_in[0];
    const float* key_value = (const float*)d_in[1];
    const float* Wq = (const float*)d_in[2];
    const float* bq = (const float*)d_in[3];
    const float* Wk = (const float*)d_in[4];
    const float* bk = (const float*)d_in[5];
    const float* Wv = (const float*)d_in[6];
    const float* bv = (const float*)d_in[7];
    const float* Wo = (const float*)d_in[8];
    const float* bo = (const float*)d_in[9];
    const float* g_q = (const float*)d_in[10];
    const float* be_q = (const float*)d_in[11];
    const float* g_k = (const float*)d_in[12];
    const float* be_k = (const float*)d_in[13];
    const float* g_o = (const float*)d_in[14];
    const float* be_o = (const float*)d_in[15];
    float* out = (float*)d_out;

    float* ws = (float*)d_ws;
    float2* part_q  = (float2*)ws;                       // 512 f2
    float2* part_kv = part_q + 2 * NBLK_RED;             // 512 f2
    float2* part_o  = part_kv + 2 * NBLK_RED;            // 512 f2
    // (header 16384 floats reserved)

    const size_t SZ = (size_t)B_ * NFULL;                // 2,097,152 elements
    char* p = (char*)(ws + 16384);
    unsigned short* qn_hi  = (unsigned short*)p; p += SZ * 2;   // \ acc split0 (8MB)
    unsigned short* qn_lo  = (unsigned short*)p; p += SZ * 2;   // /
    unsigned short* kvn_hi = (unsigned short*)p; p += SZ * 2;   // \ acc split1
    unsigned short* kvn_lo = (unsigned short*)p; p += SZ * 2;   // /
    unsigned short* Wt_hi  = (unsigned short*)p; p += (size_t)4 * 512 * 512 * 2;
    unsigned short* Wt_lo  = (unsigned short*)p; p += (size_t)4 * 512 * 512 * 2;
    unsigned short* Qb     = (unsigned short*)p; p += SZ * 2;
    unsigned short* Kb     = (unsigned short*)p; p += SZ * 2;
    unsigned short* Vt     = (unsigned short*)p; p += SZ * 2;
    float*          out_pre = (float*)p;         p += SZ * 4;   // acc split2
    unsigned short* on_hi  = (unsigned short*)p; p += SZ * 2;   // \ acc split3
    unsigned short* on_lo  = (unsigned short*)p; p += SZ * 2;   // /
    float*          lP     = (float*)p;          p += (size_t)4 * B_ * H_ * NSEQ * 4;

    float* accS0 = (float*)qn_hi;
    float* accS1 = (float*)kvn_hi;
    float* accS2 = out_pre;
    float* accS3 = (float*)on_hi;

    dim3 blk(256);

    prep_w_k<<<dim3(8, 8, 4), blk, 0, stream>>>(Wq, Wk, Wv, Wo, Wt_hi, Wt_lo);

    reduce_partial_both_k<<<dim3(NBLK_RED, B_, 2), blk, 0, stream>>>(query, key_value, part_q, part_kv);

    normalize_qkv_k<<<dim3(2048, 2), blk, 0, stream>>>(query, key_value, part_q, part_kv,
                                                       g_q, be_q, g_k, be_k,
                                                       qn_hi, qn_lo, kvn_hi, kvn_lo);

    gemm3_split_k<<<dim3(32, 4, 3), blk, 0, stream>>>(qn_hi, qn_lo, kvn_hi, kvn_lo,
                                                      Wt_hi, Wt_lo, bq, bk, bv, Qb, Kb, Vt);

    attn4_k<<<dim3(NSEQ / 64, H_, B_ * 4), dim3(64), 0, stream>>>(Qb, Kb, Vt,
                                                                  accS0, accS1, accS2, accS3, lP);

    merge4_k<<<dim3(NBLK_RED, B_), blk, 0, stream>>>(accS0, accS1, accS2, accS3, lP,
                                                     query, out_pre, part_o);

    normalize_inl_k<<<dim3(2048), blk, 0, stream>>>(out_pre, part_o, g_o, be_o, on_hi, on_lo);

    gemm_out_split_k<<<dim3(64, 4), blk, 0, stream>>>(on_hi, on_lo,
                                                      Wt_hi + (size_t)3 * 512 * 512,
                                                      Wt_lo + (size_t)3 * 512 * 512,
                                                      bo, out_pre, out);
}